// Round 20
// baseline (191.930 us; speedup 1.0000x reference)
//
#include <hip/hip_runtime.h>

#define DEV static __device__ __forceinline__

typedef __attribute__((ext_vector_type(8))) __bf16 bf16x8;
typedef __attribute__((ext_vector_type(4))) float f32x4;

constexpr int CB = 2;     // batch
constexpr int CS = 2048;  // seq
constexpr int CE = 1024;  // embed
constexpr int CH = 16;    // heads
constexpr int CD = 64;    // head dim
constexpr float LOG2E = 1.44269504f;

DEV unsigned short f2bf(float x) {  // RNE f32 -> bf16 bits
  unsigned int u = __float_as_uint(x);
  u += 0x7fffu + ((u >> 16) & 1u);
  return (unsigned short)(u >> 16);
}

DEV f32x4 mfma32(bf16x8 a, bf16x8 b, f32x4 c) {  // 16x16x32
  return __builtin_amdgcn_mfma_f32_16x16x32_bf16(a, b, c, 0, 0, 0);
}

DEV unsigned int cvtpk(float lo, float hi) {  // pack 2 f32 -> 2 bf16 (RNE)
  unsigned int r;
  asm("v_cvt_pk_bf16_f32 %0, %1, %2" : "=v"(r) : "v"(lo), "v"(hi));
  return r;
}

DEV float exp2r(float x) {  // raw v_exp_f32
#if __has_builtin(__builtin_amdgcn_exp2f)
  return __builtin_amdgcn_exp2f(x);
#else
  float r; asm("v_exp_f32 %0, %1" : "=v"(r) : "v"(x)); return r;
#endif
}

DEV void stage16(const void* g, void* l) {  // async global(16B/lane) -> LDS
  __builtin_amdgcn_global_load_lds(
      (const __attribute__((address_space(1))) unsigned int*)g,
      (__attribute__((address_space(3))) unsigned int*)l, 16, 0, 0);
}

// ---- prep: weight f32->bf16 only (mbias now inline in attn) ----
__global__ __launch_bounds__(256) void wcvt_all(const float* __restrict__ w0,
                                                const float* __restrict__ w1,
                                                const float* __restrict__ w2,
                                                const float* __restrict__ w3,
                                                unsigned short* __restrict__ out) {
  const long WE = (long)CE * CE;
  const long i = ((long)blockIdx.x * 256 + threadIdx.x) * 8;
  const int wi = (int)(i >> 20);
  const float* src = wi == 0 ? w0 : wi == 1 ? w1 : wi == 2 ? w2 : w3;
  const long off = i & (WE - 1);
  float4 a = *reinterpret_cast<const float4*>(src + off);
  float4 b = *reinterpret_cast<const float4*>(src + off + 4);
  uint4 v;
  v.x = cvtpk(a.x, a.y); v.y = cvtpk(a.z, a.w);
  v.z = cvtpk(b.x, b.y); v.w = cvtpk(b.z, b.w);
  *reinterpret_cast<uint4*>(out + i) = v;
}

// ---------------- QKV GEMM v6 (R19, unchanged): 256x256/BK=32 pipelined ----------------
__global__ __launch_bounds__(512) void gemm_qkv(const float* __restrict__ xf,
                                                const float* __restrict__ kvf,
                                                const unsigned short* __restrict__ Wall,
                                                const float* __restrict__ bq,
                                                const float* __restrict__ bk,
                                                const float* __restrict__ bv,
                                                unsigned short* __restrict__ Qb) {
  __shared__ __align__(16) unsigned char ldsA[32768];  // 2 x 16KB
  __shared__ __align__(16) unsigned char ldsB[32768];
  const long NE = (long)CB * CS * CE;
  const long WE = (long)CE * CE;
  const int which = blockIdx.y >> 2;          // 0=Q 1=K 2=V
  const int n0 = (blockIdx.y & 3) * 256;
  const int m0 = blockIdx.x * 256;
  const float* Ax = which == 0 ? xf : kvf;
  const unsigned char* Bb = (const unsigned char*)(Wall + (long)which * WE);
  const float* bias = which == 0 ? bq : which == 1 ? bk : bv;

  const int tid = threadIdx.x;
  const int lane = tid & 63, w = tid >> 6;
  const int wr = w >> 2, wc = w & 3;
  const int g = lane >> 4, rr = lane & 15;

  const int srow = tid >> 2;                                    // 0..127
  const int ecol = ((tid & 3) * 8) ^ (((tid >> 5) & 1) * 16);   // swizzled elem col
  const float* afp0 = Ax + (long)(m0 + srow) * CE + ecol;
  const float* afp1 = Ax + (long)(m0 + 128 + srow) * CE + ecol;
  const float* afb0 = afp0;
  const float* afb1 = afp1;
  const int scsw = ((tid & 3) * 16) ^ (((tid >> 5) & 1) << 5);
  const unsigned char* bpR0 = Bb + ((long)(n0 + srow) * CE) * 2 + scsw;
  const unsigned char* bpR1 = Bb + ((long)(n0 + 128 + srow) * CE) * 2 + scsw;

  const int cswz = (g * 16) ^ (((rr >> 3) & 1) << 5);
  const unsigned char* rbA = ldsA + wr * 8192 + rr * 64 + cswz;
  const unsigned char* rbB = ldsB + wc * 4096 + rr * 64 + cswz;

  f32x4 acc[8][4] = {};
  float4 afr0, afr1, afr2, afr3;

  auto loadA = [&](bool junk) {
    const float* p0 = junk ? afb0 : afp0;
    const float* p1 = junk ? afb1 : afp1;
    afr0 = *reinterpret_cast<const float4*>(p0);
    afr1 = *reinterpret_cast<const float4*>(p0 + 4);
    afr2 = *reinterpret_cast<const float4*>(p1);
    afr3 = *reinterpret_cast<const float4*>(p1 + 4);
    if (!junk) { afp0 += 32; afp1 += 32; }
  };
  auto writeA = [&](int buf) {
    uint4 w0v, w1v;
    w0v.x = cvtpk(afr0.x, afr0.y); w0v.y = cvtpk(afr0.z, afr0.w);
    w0v.z = cvtpk(afr1.x, afr1.y); w0v.w = cvtpk(afr1.z, afr1.w);
    w1v.x = cvtpk(afr2.x, afr2.y); w1v.y = cvtpk(afr2.z, afr2.w);
    w1v.z = cvtpk(afr3.x, afr3.y); w1v.w = cvtpk(afr3.z, afr3.w);
    *reinterpret_cast<uint4*>(ldsA + buf * 16384 + tid * 16) = w0v;
    *reinterpret_cast<uint4*>(ldsA + buf * 16384 + 8192 + tid * 16) = w1v;
  };
  auto stB = [&](int buf) {
    stage16(bpR0, ldsB + buf * 16384 + w * 1024);
    stage16(bpR1, ldsB + buf * 16384 + 8192 + w * 1024);
    bpR0 += 64; bpR1 += 64;
  };

  loadA(false);
  stB(0);
  asm volatile("s_waitcnt vmcnt(2)" ::: "memory");
  writeA(0);
  loadA(false);
  stB(1);
  asm volatile("s_waitcnt vmcnt(6)" ::: "memory");
  asm volatile("s_waitcnt lgkmcnt(0)" ::: "memory");
  __builtin_amdgcn_s_barrier();

  auto group = [&](int buf, bool junk) {
    bf16x8 ar[4], br[4];
#pragma unroll
    for (int ii = 0; ii < 4; ii++)
      ar[ii] = *reinterpret_cast<const bf16x8*>(rbA + buf * 16384 + ii * 1024);
#pragma unroll
    for (int j = 0; j < 4; j++)
      br[j] = *reinterpret_cast<const bf16x8*>(rbB + buf * 16384 + j * 1024);
    asm volatile("s_waitcnt vmcnt(2)" ::: "memory");
    writeA(buf ^ 1);
    loadA(junk);
    asm volatile("s_waitcnt lgkmcnt(0)" ::: "memory");
    __builtin_amdgcn_sched_barrier(0);
    __builtin_amdgcn_s_setprio(1);
#pragma unroll
    for (int ii = 0; ii < 4; ii++)
#pragma unroll
      for (int j = 0; j < 4; j++)
        acc[ii][j] = mfma32(ar[ii], br[j], acc[ii][j]);
    __builtin_amdgcn_s_setprio(0);
    __builtin_amdgcn_s_barrier();
#pragma unroll
    for (int ii = 0; ii < 4; ii++)
      ar[ii] = *reinterpret_cast<const bf16x8*>(rbA + buf * 16384 + 4096 + ii * 1024);
    stB(buf);
    asm volatile("s_waitcnt lgkmcnt(0)" ::: "memory");
    __builtin_amdgcn_sched_barrier(0);
    __builtin_amdgcn_s_setprio(1);
#pragma unroll
    for (int ii = 0; ii < 4; ii++)
#pragma unroll
      for (int j = 0; j < 4; j++)
        acc[4 + ii][j] = mfma32(ar[ii], br[j], acc[4 + ii][j]);
    __builtin_amdgcn_s_setprio(0);
    asm volatile("s_waitcnt vmcnt(6)" ::: "memory");
    __builtin_amdgcn_s_barrier();
  };

#pragma unroll 1
  for (int it = 0; it < 16; ++it) {
    group(0, it == 15);
    group(1, it == 15);
  }
  asm volatile("s_waitcnt vmcnt(0)" ::: "memory");

  const float scale = which == 0 ? 0.125f * LOG2E : 1.0f;
#pragma unroll
  for (int i = 0; i < 8; i++) {
#pragma unroll
    for (int j = 0; j < 4; j++) {
      const int colg = n0 + wc * 64 + j * 16 + rr;
      const float bvv = bias[colg];
      if (which == 2) {  // V^T layout [B,H,DK,S]
        const int rowbase = m0 + wr * 128 + i * 16 + g * 4;
        const int bb = rowbase >> 11, s = rowbase & 2047;
        const int hh = colg >> 6, d = colg & 63;
        uint2 val;
        val.x = (unsigned int)f2bf(acc[i][j][0] + bvv) | ((unsigned int)f2bf(acc[i][j][1] + bvv) << 16);
        val.y = (unsigned int)f2bf(acc[i][j][2] + bvv) | ((unsigned int)f2bf(acc[i][j][3] + bvv) << 16);
        *reinterpret_cast<uint2*>(Qb + 2 * NE + ((long)((bb * CH + hh) * CD + d)) * CS + s) = val;
      } else {
        unsigned short* outp = Qb + (long)which * NE;
#pragma unroll
        for (int r = 0; r < 4; r++) {
          const int row = m0 + wr * 128 + i * 16 + g * 4 + r;
          outp[(long)row * CE + colg] = f2bf((acc[i][j][r] + bvv) * scale);
        }
      }
    }
  }
}

// ---------------- WO GEMM: 128x64 tile, 512 blocks (unchanged) ----------------
__global__ __launch_bounds__(256) void gemm_wo(const unsigned short* __restrict__ A,
                                               const unsigned short* __restrict__ W,
                                               const float* __restrict__ bias,
                                               float* __restrict__ out) {
  __shared__ __align__(16) unsigned short As[128 * 64];
  __shared__ __align__(16) unsigned short Bs[64 * 64];
  const int tid = threadIdx.x;
  const int lane = tid & 63, wave = tid >> 6;
  const int wm = (wave >> 1) * 64, wn = (wave & 1) * 32;
  const int g = lane >> 4, rr = lane & 15;
  const int m0 = blockIdx.x * 128, n0 = blockIdx.y * 64;
  const int K = CE;
  f32x4 acc[4][2] = {};

  for (int k0 = 0; k0 < K; k0 += 64) {
#pragma unroll
    for (int t = 0; t < 4; t++) {
      const int u = t * 256 + tid;
      const int row = u >> 3, ce = (u & 7) * 8;
      stage16(A + (long)(m0 + row) * K + k0 + ce, (char*)As + (t * 256 + (tid & 192)) * 16);
    }
#pragma unroll
    for (int t = 0; t < 2; t++) {
      const int u = t * 256 + tid;
      const int row = u >> 3, ce = (u & 7) * 8;
      stage16(W + (long)(n0 + row) * K + k0 + ce, (char*)Bs + (t * 256 + (tid & 192)) * 16);
    }
    __syncthreads();
#pragma unroll
    for (int kk = 0; kk < 2; kk++) {
      bf16x8 af[4], bfr[2];
#pragma unroll
      for (int i = 0; i < 4; i++)
        af[i] = *reinterpret_cast<const bf16x8*>(&As[(wm + i * 16 + rr) * 64 + kk * 32 + g * 8]);
#pragma unroll
      for (int j = 0; j < 2; j++)
        bfr[j] = *reinterpret_cast<const bf16x8*>(&Bs[(wn + j * 16 + rr) * 64 + kk * 32 + g * 8]);
#pragma unroll
      for (int i = 0; i < 4; i++)
#pragma unroll
        for (int j = 0; j < 2; j++)
          acc[i][j] = mfma32(af[i], bfr[j], acc[i][j]);
    }
    __syncthreads();
  }

#pragma unroll
  for (int i = 0; i < 4; i++)
#pragma unroll
    for (int j = 0; j < 2; j++) {
      const int colg = n0 + wn + j * 16 + rr;
      const float bvv = bias[colg];
#pragma unroll
      for (int r = 0; r < 4; r++) {
        const int row = m0 + wm + i * 16 + g * 4 + r;
        out[(long)row * CE + colg] = acc[i][j][r] + bvv;
      }
    }
}

// ---------------- Flash attention v13: inline f32 bias/mask, 1 barrier/tile ----------------
// Per tile: compute = [issue bias+mask loads (24 vmem)] [QK, C=0] [sched_barrier]
// [softmax: sf + mbias (f32, fmaf+cndmask), exp2, cvtpk] [PV] -> s_barrier -> stage(t+2).
// The compiler's wait for the bias loads (vmcnt(0)-equivalent, placed after the QK pin)
// also retires stage(t+1) (issued a full tile earlier -> landed, no stall) -> the next
// tile's head needs only the barrier for cross-wave stage-landed guarantees.
__global__ __launch_bounds__(256, 2) void attn_kernel(const unsigned short* __restrict__ Qb,
                                                      const unsigned short* __restrict__ Kb,
                                                      const unsigned short* __restrict__ Vtw,
                                                      const float* __restrict__ bias,
                                                      const int* __restrict__ mask,
                                                      unsigned short* __restrict__ AO) {
  __shared__ __align__(16) unsigned char lds[65536];
  const int h = blockIdx.x, qt = blockIdx.y, b = blockIdx.z;
  const int tid = threadIdx.x;
  const int lane = tid & 63, w = tid >> 6;
  const int g = lane >> 4, c = lane & 15;
  const int qbase = qt * 128 + w * 32;

  bf16x8 qf[2][2];
  bool mq[2];
#pragma unroll
  for (int qb = 0; qb < 2; qb++) {
    const unsigned short* Qrow = Qb + ((long)b * CS + qbase + qb * 16 + c) * CE + h * CD;
    qf[qb][0] = *reinterpret_cast<const bf16x8*>(Qrow + g * 8);
    qf[qb][1] = *reinterpret_cast<const bf16x8*>(Qrow + 32 + g * 8);
    mq[qb] = mask[b * CS + qbase + qb * 16 + c] != 0;
    if (!mq[qb]) { qf[qb][0] = bf16x8{}; qf[qb][1] = bf16x8{}; }  // uniform masked rows
  }

  const unsigned char *kg[4], *vg[4];
  {
    const unsigned char* Ksrc = (const unsigned char*)(Kb + (long)b * CS * CE + h * CD);
    const unsigned char* Vsrc = (const unsigned char*)(Vtw + (long)(b * CH + h) * CD * CS);
    const int rr8 = lane >> 3;
    const int csw = ((lane & 7) << 4) ^ (rr8 << 4);
#pragma unroll
    for (int t = 0; t < 4; t++) {
      const int krow = t * 32 + w * 8 + rr8;
      const int key = (krow & 96) + ((krow >> 2) & 3) * 8 + ((krow >> 4) & 1) * 4 + (krow & 3);
      kg[t] = Ksrc + (long)key * (CE * 2) + csw;
      const int vrow = (t & 1) * 32 + w * 8 + rr8;
      vg[t] = Vsrc + (long)vrow * (CS * 2) + (t >> 1) * 128 + csw;
    }
  }
  const int sw = (c & 7) << 4;
  const unsigned char* rb0 = lds + c * 128 + ((g * 16) ^ sw);
  const unsigned char* rb1 = lds + c * 128 + ((64 + g * 16) ^ sw);

  // bias/mask running pointers (k = kt + kb*32 + g*8 + j layout == P frag layout)
  const float* bp0 = bias + ((long)b * CS + qbase + c) * CS + g * 8;
  const float* bp1 = bias + ((long)b * CS + qbase + 16 + c) * CS + g * 8;
  const int* mp = mask + b * CS + g * 8;

  f32x4 o[2][4] = {};
  f32x4 lsum4[2] = {};

  auto stage = [&](int bo) {  // 8 vmem
    unsigned char* kbuf = lds + bo;
    unsigned char* vbuf = lds + bo + 16384;
#pragma unroll
    for (int t = 0; t < 4; t++) {
      stage16(kg[t], kbuf + t * 4096 + w * 1024);
      stage16(vg[t], vbuf + (t >> 1) * 8192 + (t & 1) * 4096 + w * 1024);
      kg[t] += 128 * CE * 2;
      vg[t] += 128 * 2;
    }
  };

  auto compute = [&](int bo) {
    // ---- issue this tile's bias+mask loads first (24 vmem; consumed in softmax) ----
    float4 bf[2][4][2];
    int4 mi[4][2];
#pragma unroll
    for (int kb = 0; kb < 4; kb++) {
      bf[0][kb][0] = *reinterpret_cast<const float4*>(bp0 + kb * 32);
      bf[0][kb][1] = *reinterpret_cast<const float4*>(bp0 + kb * 32 + 4);
      bf[1][kb][0] = *reinterpret_cast<const float4*>(bp1 + kb * 32);
      bf[1][kb][1] = *reinterpret_cast<const float4*>(bp1 + kb * 32 + 4);
      mi[kb][0] = *reinterpret_cast<const int4*>(mp + kb * 32);
      mi[kb][1] = *reinterpret_cast<const int4*>(mp + kb * 32 + 4);
    }
    bp0 += 128; bp1 += 128; mp += 128;
    // ---- S^T = K @ Q^T (C = 0) ----
    f32x4 sf[2][8];
    __builtin_amdgcn_s_setprio(1);
#pragma unroll
    for (int cb = 0; cb < 8; cb++) {
      const bf16x8 kf0 = *reinterpret_cast<const bf16x8*>(rb0 + bo + cb * 2048);
      const bf16x8 kf1 = *reinterpret_cast<const bf16x8*>(rb1 + bo + cb * 2048);
#pragma unroll
      for (int qb = 0; qb < 2; qb++) {
        f32x4 t = mfma32(kf0, qf[qb][0], f32x4{});
        sf[qb][cb] = mfma32(kf1, qf[qb][1], t);
      }
    }
    __builtin_amdgcn_s_setprio(0);
    __builtin_amdgcn_sched_barrier(0);  // pin bias-load waits BELOW the QK cluster
    // ---- softmax: p = exp2(sf + mbias), mbias computed inline in f32 ----
    const float NEGC = -1e9f * LOG2E;
    uint4 pw[2][4];
#pragma unroll
    for (int qb = 0; qb < 2; qb++)
#pragma unroll
      for (int kb = 0; kb < 4; kb++)
#pragma unroll
        for (int half = 0; half < 2; half++) {
          const int cb = 2 * kb + half;
          const float4 bv = bf[qb][kb][half];
          const int4 mk = mi[kb][half];
          const float bvs[4] = {bv.x, bv.y, bv.z, bv.w};
          const int mks[4] = {mk.x, mk.y, mk.z, mk.w};
          f32x4 pv;
#pragma unroll
          for (int r = 0; r < 4; r++) {
            float t = fmaf(bvs[r], LOG2E, sf[qb][cb][r]);
            t = (mks[r] != 0) ? t : NEGC;
            t = mq[qb] ? t : sf[qb][cb][r];  // masked q: value = sf = 0 -> uniform
            pv[r] = exp2r(t);
          }
          lsum4[qb] = lsum4[qb] + pv;
          if (half == 0) { pw[qb][kb].x = cvtpk(pv[0], pv[1]); pw[qb][kb].y = cvtpk(pv[2], pv[3]); }
          else           { pw[qb][kb].z = cvtpk(pv[0], pv[1]); pw[qb][kb].w = cvtpk(pv[2], pv[3]); }
        }
    // ---- O^T += V^T P^T ----
    __builtin_amdgcn_s_setprio(1);
#pragma unroll
    for (int nb = 0; nb < 4; nb++) {
#pragma unroll
      for (int kb = 0; kb < 4; kb++) {
        const unsigned char* rbx = (kb & 1) ? rb1 : rb0;
        const bf16x8 vf = *reinterpret_cast<const bf16x8*>(
            rbx + bo + 16384 + (kb >> 1) * 8192 + nb * 2048);
#pragma unroll
        for (int qb = 0; qb < 2; qb++)
          o[qb][nb] = mfma32(vf, __builtin_bit_cast(bf16x8, pw[qb][kb]), o[qb][nb]);
      }
    }
    __builtin_amdgcn_s_setprio(0);
  };

  // prologue: stage tiles 0,1; ensure tile 0 landed across waves
  stage(0);
  stage(32768);
  asm volatile("s_waitcnt vmcnt(8)" ::: "memory");  // retire stage(0), keep stage(1)
  __builtin_amdgcn_s_barrier();

#pragma unroll 1
  for (int it = 0; it < 8; ++it) {  // 16 tiles of 128 keys; 1 barrier per tile
    compute(0);                      // internal bias-load wait retires stage(t+1)
    __builtin_amdgcn_s_barrier();    // close: all waves done reading buf0
    stage(0);                        // tile t+2 (junk at tail, valid ws memory)
    compute(32768);
    __builtin_amdgcn_s_barrier();
    stage(32768);
  }

#pragma unroll
  for (int qb = 0; qb < 2; qb++) {
    float lsum = (lsum4[qb][0] + lsum4[qb][1]) + (lsum4[qb][2] + lsum4[qb][3]);
    lsum += __shfl_xor(lsum, 16, 64);
    lsum += __shfl_xor(lsum, 32, 64);
    const float linv = 1.0f / lsum;
    unsigned short* Orow = AO + ((long)b * CS + qbase + qb * 16 + c) * CE + h * CD;
#pragma unroll
    for (int nb = 0; nb < 4; nb++) {
      uint2 val;
      val.x = (unsigned int)f2bf(o[qb][nb][0] * linv) | ((unsigned int)f2bf(o[qb][nb][1] * linv) << 16);
      val.y = (unsigned int)f2bf(o[qb][nb][2] * linv) | ((unsigned int)f2bf(o[qb][nb][3] * linv) << 16);
      *reinterpret_cast<uint2*>(Orow + nb * 16 + g * 4) = val;
    }
  }
  asm volatile("s_waitcnt vmcnt(0)" ::: "memory");  // drain junk stages before endpgm
}

// ---------------- host ----------------
extern "C" void kernel_launch(void* const* d_in, const int* in_sizes, int n_in,
                              void* d_out, int out_size, void* d_ws, size_t ws_size,
                              hipStream_t stream) {
  (void)in_sizes; (void)n_in; (void)out_size; (void)ws_size;
  const float* x    = (const float*)d_in[0];
  const float* kv   = (const float*)d_in[1];
  const int*   mask = (const int*)d_in[2];
  const float* ab   = (const float*)d_in[3];
  const float* WQw  = (const float*)d_in[4];
  const float* WQb  = (const float*)d_in[5];
  const float* WKw  = (const float*)d_in[6];
  const float* WKb  = (const float*)d_in[7];
  const float* WVw  = (const float*)d_in[8];
  const float* WVb  = (const float*)d_in[9];
  const float* WOw  = (const float*)d_in[10];
  const float* WOb  = (const float*)d_in[11];
  float* out = (float*)d_out;

  const long NE = (long)CB * CS * CE;  // 4,194,304
  const long WE = (long)CE * CE;       // 1,048,576
  unsigned short* ws  = (unsigned short*)d_ws;
  unsigned short* wqb = ws;            // WQ|WK|WV contiguous = Wall
  unsigned short* wob = wqb + 3 * WE;
  unsigned short* Qb  = wob + WE;      // Q | K | Vt | AO contiguous; ws use = 41.9 MB
  unsigned short* AO  = Qb + 3 * NE;

  wcvt_all<<<(int)((4 * WE) / 2048), 256, 0, stream>>>(WQw, WKw, WVw, WOw, wqb);

  gemm_qkv<<<dim3(16, 12), 512, 0, stream>>>(x, kv, wqb, WQb, WKb, WVb, Qb);

  attn_kernel<<<dim3(CH, CS / 128, CB), 256, 0, stream>>>(
      Qb, Qb + NE, Qb + 2 * NE, ab, mask, AO);

  gemm_wo<<<dim3(32, 16), 256, 0, stream>>>(AO, wob, WOb, out);
}

// Round 21
// 132.157 us; speedup vs baseline: 1.4523x; 1.4523x over previous
//
#include <hip/hip_runtime.h>

#define DEV static __device__ __forceinline__

typedef __attribute__((ext_vector_type(8))) __bf16 bf16x8;
typedef __attribute__((ext_vector_type(4))) float f32x4;

constexpr int CB = 2;     // batch
constexpr int CS = 2048;  // seq
constexpr int CE = 1024;  // embed
constexpr int CH = 16;    // heads
constexpr int CD = 64;    // head dim
constexpr float LOG2E = 1.44269504f;

DEV unsigned short f2bf(float x) {  // RNE f32 -> bf16 bits
  unsigned int u = __float_as_uint(x);
  u += 0x7fffu + ((u >> 16) & 1u);
  return (unsigned short)(u >> 16);
}

DEV f32x4 mfma32(bf16x8 a, bf16x8 b, f32x4 c) {  // 16x16x32
  return __builtin_amdgcn_mfma_f32_16x16x32_bf16(a, b, c, 0, 0, 0);
}

DEV unsigned int cvtpk(float lo, float hi) {  // pack 2 f32 -> 2 bf16 (RNE)
  unsigned int r;
  asm("v_cvt_pk_bf16_f32 %0, %1, %2" : "=v"(r) : "v"(lo), "v"(hi));
  return r;
}

DEV float exp2r(float x) {  // raw v_exp_f32
#if __has_builtin(__builtin_amdgcn_exp2f)
  return __builtin_amdgcn_exp2f(x);
#else
  float r; asm("v_exp_f32 %0, %1" : "=v"(r) : "v"(x)); return r;
#endif
}

DEV f32x4 unpk(unsigned int a, unsigned int b) {  // 4 packed bf16 -> f32x4
  f32x4 r;
  r[0] = __uint_as_float(a << 16);
  r[1] = __uint_as_float(a & 0xffff0000u);
  r[2] = __uint_as_float(b << 16);
  r[3] = __uint_as_float(b & 0xffff0000u);
  return r;
}

DEV void stage16(const void* g, void* l) {  // async global(16B/lane) -> LDS
  __builtin_amdgcn_global_load_lds(
      (const __attribute__((address_space(1))) unsigned int*)g,
      (__attribute__((address_space(3))) unsigned int*)l, 16, 0, 0);
}

// ---- prep: weight cvt (4*WE elems) + mbias (CB*CS*CS elems), one launch ----
DEV void wcvt_body(long i, const float* __restrict__ w0, const float* __restrict__ w1,
                   const float* __restrict__ w2, const float* __restrict__ w3,
                   unsigned short* __restrict__ out) {
  const long WE = (long)CE * CE;
  const int wi = (int)(i >> 20);
  const float* src = wi == 0 ? w0 : wi == 1 ? w1 : wi == 2 ? w2 : w3;
  const long off = i & (WE - 1);
  float4 a = *reinterpret_cast<const float4*>(src + off);
  float4 b = *reinterpret_cast<const float4*>(src + off + 4);
  uint4 v;
  v.x = cvtpk(a.x, a.y); v.y = cvtpk(a.z, a.w);
  v.z = cvtpk(b.x, b.y); v.w = cvtpk(b.z, b.w);
  *reinterpret_cast<uint4*>(out + i) = v;
}

DEV void mbias_body(long idx, const float* __restrict__ bias, const int* __restrict__ mask,
                    unsigned short* __restrict__ mb16) {
  const int b = (int)(idx >> 22);
  const int q = (int)((idx >> 11) & (CS - 1));
  const int k0 = (int)(idx & (CS - 1));
  const bool mq = mask[b * CS + q] != 0;
  const int4 mk0 = *reinterpret_cast<const int4*>(mask + b * CS + k0);
  const int4 mk1 = *reinterpret_cast<const int4*>(mask + b * CS + k0 + 4);
  const float4 b0 = *reinterpret_cast<const float4*>(bias + idx);
  const float4 b1 = *reinterpret_cast<const float4*>(bias + idx + 4);
  const float NEG = -1e9f * LOG2E;
  float v[8];
  if (mq) {
    v[0] = (mk0.x != 0) ? b0.x * LOG2E : NEG;
    v[1] = (mk0.y != 0) ? b0.y * LOG2E : NEG;
    v[2] = (mk0.z != 0) ? b0.z * LOG2E : NEG;
    v[3] = (mk0.w != 0) ? b0.w * LOG2E : NEG;
    v[4] = (mk1.x != 0) ? b1.x * LOG2E : NEG;
    v[5] = (mk1.y != 0) ? b1.y * LOG2E : NEG;
    v[6] = (mk1.z != 0) ? b1.z * LOG2E : NEG;
    v[7] = (mk1.w != 0) ? b1.w * LOG2E : NEG;
  } else {
#pragma unroll
    for (int j = 0; j < 8; j++) v[j] = 0.f;  // uniform row (qf also zeroed in attn)
  }
  uint4 o;
  o.x = cvtpk(v[0], v[1]); o.y = cvtpk(v[2], v[3]);
  o.z = cvtpk(v[4], v[5]); o.w = cvtpk(v[6], v[7]);
  *reinterpret_cast<uint4*>(mb16 + idx) = o;
}

__global__ __launch_bounds__(256) void prep_all(const float* __restrict__ w0,
                                                const float* __restrict__ w1,
                                                const float* __restrict__ w2,
                                                const float* __restrict__ w3,
                                                unsigned short* __restrict__ wout,
                                                const float* __restrict__ bias,
                                                const int* __restrict__ mask,
                                                unsigned short* __restrict__ mb16) {
  const long WCB = (4L * CE * CE) / 2048;  // 2048 blocks of weight cvt
  if (blockIdx.x < WCB) {
    wcvt_body(((long)blockIdx.x * 256 + threadIdx.x) * 8, w0, w1, w2, w3, wout);
  } else {
    mbias_body(((long)(blockIdx.x - WCB) * 256 + threadIdx.x) * 8, bias, mask, mb16);
  }
}

// ---------------- QKV GEMM v6: 256x256/BK=32 pipelined, 4 barriers/K-tile ----------------
__global__ __launch_bounds__(512) void gemm_qkv(const float* __restrict__ xf,
                                                const float* __restrict__ kvf,
                                                const unsigned short* __restrict__ Wall,
                                                const float* __restrict__ bq,
                                                const float* __restrict__ bk,
                                                const float* __restrict__ bv,
                                                unsigned short* __restrict__ Qb) {
  __shared__ __align__(16) unsigned char ldsA[32768];  // 2 x 16KB
  __shared__ __align__(16) unsigned char ldsB[32768];
  const long NE = (long)CB * CS * CE;
  const long WE = (long)CE * CE;
  const int which = blockIdx.y >> 2;          // 0=Q 1=K 2=V
  const int n0 = (blockIdx.y & 3) * 256;
  const int m0 = blockIdx.x * 256;
  const float* Ax = which == 0 ? xf : kvf;
  const unsigned char* Bb = (const unsigned char*)(Wall + (long)which * WE);
  const float* bias = which == 0 ? bq : which == 1 ? bk : bv;

  const int tid = threadIdx.x;
  const int lane = tid & 63, w = tid >> 6;
  const int wr = w >> 2, wc = w & 3;
  const int g = lane >> 4, rr = lane & 15;

  const int srow = tid >> 2;                                    // 0..127
  const int ecol = ((tid & 3) * 8) ^ (((tid >> 5) & 1) * 16);   // swizzled elem col
  const float* afp0 = Ax + (long)(m0 + srow) * CE + ecol;
  const float* afp1 = Ax + (long)(m0 + 128 + srow) * CE + ecol;
  const float* afb0 = afp0;  // clamped junk sources (stay in-bounds)
  const float* afb1 = afp1;
  const int scsw = ((tid & 3) * 16) ^ (((tid >> 5) & 1) << 5);
  const unsigned char* bpR0 = Bb + ((long)(n0 + srow) * CE) * 2 + scsw;
  const unsigned char* bpR1 = Bb + ((long)(n0 + 128 + srow) * CE) * 2 + scsw;

  const int cswz = (g * 16) ^ (((rr >> 3) & 1) << 5);
  const unsigned char* rbA = ldsA + wr * 8192 + rr * 64 + cswz;
  const unsigned char* rbB = ldsB + wc * 4096 + rr * 64 + cswz;

  f32x4 acc[8][4] = {};
  float4 afr0, afr1, afr2, afr3;

  auto loadA = [&](bool junk) {
    const float* p0 = junk ? afb0 : afp0;
    const float* p1 = junk ? afb1 : afp1;
    afr0 = *reinterpret_cast<const float4*>(p0);
    afr1 = *reinterpret_cast<const float4*>(p0 + 4);
    afr2 = *reinterpret_cast<const float4*>(p1);
    afr3 = *reinterpret_cast<const float4*>(p1 + 4);
    if (!junk) { afp0 += 32; afp1 += 32; }
  };
  auto writeA = [&](int buf) {
    uint4 w0v, w1v;
    w0v.x = cvtpk(afr0.x, afr0.y); w0v.y = cvtpk(afr0.z, afr0.w);
    w0v.z = cvtpk(afr1.x, afr1.y); w0v.w = cvtpk(afr1.z, afr1.w);
    w1v.x = cvtpk(afr2.x, afr2.y); w1v.y = cvtpk(afr2.z, afr2.w);
    w1v.z = cvtpk(afr3.x, afr3.y); w1v.w = cvtpk(afr3.z, afr3.w);
    *reinterpret_cast<uint4*>(ldsA + buf * 16384 + tid * 16) = w0v;
    *reinterpret_cast<uint4*>(ldsA + buf * 16384 + 8192 + tid * 16) = w1v;
  };
  auto stB = [&](int buf) {
    stage16(bpR0, ldsB + buf * 16384 + w * 1024);
    stage16(bpR1, ldsB + buf * 16384 + 8192 + w * 1024);
    bpR0 += 64; bpR1 += 64;
  };

  // prologue -> establish entry invariant: outstanding = [Af(1):4][B(1):2]
  loadA(false);
  stB(0);
  asm volatile("s_waitcnt vmcnt(2)" ::: "memory");
  writeA(0);
  loadA(false);
  stB(1);
  asm volatile("s_waitcnt vmcnt(6)" ::: "memory");
  asm volatile("s_waitcnt lgkmcnt(0)" ::: "memory");
  __builtin_amdgcn_s_barrier();

  auto group = [&](int buf, bool junk) {
    bf16x8 ar[4], br[4];
#pragma unroll
    for (int ii = 0; ii < 4; ii++)
      ar[ii] = *reinterpret_cast<const bf16x8*>(rbA + buf * 16384 + ii * 1024);
#pragma unroll
    for (int j = 0; j < 4; j++)
      br[j] = *reinterpret_cast<const bf16x8*>(rbB + buf * 16384 + j * 1024);
    asm volatile("s_waitcnt vmcnt(2)" ::: "memory");  // Af(t+1) regs landed
    writeA(buf ^ 1);
    loadA(junk);
    asm volatile("s_waitcnt lgkmcnt(0)" ::: "memory");
    __builtin_amdgcn_sched_barrier(0);
    __builtin_amdgcn_s_setprio(1);
#pragma unroll
    for (int ii = 0; ii < 4; ii++)
#pragma unroll
      for (int j = 0; j < 4; j++)
        acc[ii][j] = mfma32(ar[ii], br[j], acc[ii][j]);
    __builtin_amdgcn_s_setprio(0);
    __builtin_amdgcn_s_barrier();                     // close phase 0
#pragma unroll
    for (int ii = 0; ii < 4; ii++)
      ar[ii] = *reinterpret_cast<const bf16x8*>(rbA + buf * 16384 + 4096 + ii * 1024);
    stB(buf);
    asm volatile("s_waitcnt lgkmcnt(0)" ::: "memory");
    __builtin_amdgcn_sched_barrier(0);
    __builtin_amdgcn_s_setprio(1);
#pragma unroll
    for (int ii = 0; ii < 4; ii++)
#pragma unroll
      for (int j = 0; j < 4; j++)
        acc[4 + ii][j] = mfma32(ar[ii], br[j], acc[4 + ii][j]);
    __builtin_amdgcn_s_setprio(0);
    asm volatile("s_waitcnt vmcnt(6)" ::: "memory");  // B(t+1) landed
    __builtin_amdgcn_s_barrier();                     // close phase 1
  };

#pragma unroll 1
  for (int it = 0; it < 16; ++it) {  // 32 K-tiles of 32
    group(0, it == 15);
    group(1, it == 15);
  }
  asm volatile("s_waitcnt vmcnt(0)" ::: "memory");

  const float scale = which == 0 ? 0.125f * LOG2E : 1.0f;
#pragma unroll
  for (int i = 0; i < 8; i++) {
#pragma unroll
    for (int j = 0; j < 4; j++) {
      const int colg = n0 + wc * 64 + j * 16 + rr;
      const float bvv = bias[colg];
      if (which == 2) {  // V^T layout [B,H,DK,S]
        const int rowbase = m0 + wr * 128 + i * 16 + g * 4;
        const int bb = rowbase >> 11, s = rowbase & 2047;
        const int hh = colg >> 6, d = colg & 63;
        uint2 val;
        val.x = (unsigned int)f2bf(acc[i][j][0] + bvv) | ((unsigned int)f2bf(acc[i][j][1] + bvv) << 16);
        val.y = (unsigned int)f2bf(acc[i][j][2] + bvv) | ((unsigned int)f2bf(acc[i][j][3] + bvv) << 16);
        *reinterpret_cast<uint2*>(Qb + 2 * NE + ((long)((bb * CH + hh) * CD + d)) * CS + s) = val;
      } else {
        unsigned short* outp = Qb + (long)which * NE;
#pragma unroll
        for (int r = 0; r < 4; r++) {
          const int row = m0 + wr * 128 + i * 16 + g * 4 + r;
          outp[(long)row * CE + colg] = f2bf((acc[i][j][r] + bvv) * scale);
        }
      }
    }
  }
}

// ---------------- WO GEMM: 128x64 tile, 512 blocks (2/CU) ----------------
__global__ __launch_bounds__(256) void gemm_wo(const unsigned short* __restrict__ A,
                                               const unsigned short* __restrict__ W,
                                               const float* __restrict__ bias,
                                               float* __restrict__ out) {
  __shared__ __align__(16) unsigned short As[128 * 64];
  __shared__ __align__(16) unsigned short Bs[64 * 64];
  const int tid = threadIdx.x;
  const int lane = tid & 63, wave = tid >> 6;
  const int wm = (wave >> 1) * 64, wn = (wave & 1) * 32;
  const int g = lane >> 4, rr = lane & 15;
  const int m0 = blockIdx.x * 128, n0 = blockIdx.y * 64;
  const int K = CE;
  f32x4 acc[4][2] = {};

  for (int k0 = 0; k0 < K; k0 += 64) {
#pragma unroll
    for (int t = 0; t < 4; t++) {
      const int u = t * 256 + tid;
      const int row = u >> 3, ce = (u & 7) * 8;
      stage16(A + (long)(m0 + row) * K + k0 + ce, (char*)As + (t * 256 + (tid & 192)) * 16);
    }
#pragma unroll
    for (int t = 0; t < 2; t++) {
      const int u = t * 256 + tid;
      const int row = u >> 3, ce = (u & 7) * 8;
      stage16(W + (long)(n0 + row) * K + k0 + ce, (char*)Bs + (t * 256 + (tid & 192)) * 16);
    }
    __syncthreads();
#pragma unroll
    for (int kk = 0; kk < 2; kk++) {
      bf16x8 af[4], bfr[2];
#pragma unroll
      for (int i = 0; i < 4; i++)
        af[i] = *reinterpret_cast<const bf16x8*>(&As[(wm + i * 16 + rr) * 64 + kk * 32 + g * 8]);
#pragma unroll
      for (int j = 0; j < 2; j++)
        bfr[j] = *reinterpret_cast<const bf16x8*>(&Bs[(wn + j * 16 + rr) * 64 + kk * 32 + g * 8]);
#pragma unroll
      for (int i = 0; i < 4; i++)
#pragma unroll
        for (int j = 0; j < 2; j++)
          acc[i][j] = mfma32(af[i], bfr[j], acc[i][j]);
    }
    __syncthreads();
  }

#pragma unroll
  for (int i = 0; i < 4; i++)
#pragma unroll
    for (int j = 0; j < 2; j++) {
      const int colg = n0 + wn + j * 16 + rr;
      const float bvv = bias[colg];
#pragma unroll
      for (int r = 0; r < 4; r++) {
        const int row = m0 + wm + i * 16 + g * 4 + r;
        out[(long)row * CE + colg] = acc[i][j][r] + bvv;
      }
    }
}

// ---------------- Flash attention: BK=128, static softmax, mb16 precomputed ----------------
__global__ __launch_bounds__(256, 2) void attn_kernel(const unsigned short* __restrict__ Qb,
                                                      const unsigned short* __restrict__ Kb,
                                                      const unsigned short* __restrict__ Vtw,
                                                      const unsigned short* __restrict__ mb16,
                                                      const int* __restrict__ mask,
                                                      unsigned short* __restrict__ AO) {
  __shared__ __align__(16) unsigned char lds[65536];
  const int h = blockIdx.x, qt = blockIdx.y, b = blockIdx.z;
  const int tid = threadIdx.x;
  const int lane = tid & 63, w = tid >> 6;
  const int g = lane >> 4, c = lane & 15;
  const int qbase = qt * 128 + w * 32;

  bf16x8 qf[2][2];
#pragma unroll
  for (int qb = 0; qb < 2; qb++) {
    const unsigned short* Qrow = Qb + ((long)b * CS + qbase + qb * 16 + c) * CE + h * CD;
    qf[qb][0] = *reinterpret_cast<const bf16x8*>(Qrow + g * 8);
    qf[qb][1] = *reinterpret_cast<const bf16x8*>(Qrow + 32 + g * 8);
    if (mask[b * CS + qbase + qb * 16 + c] == 0) {
      qf[qb][0] = bf16x8{}; qf[qb][1] = bf16x8{};
    }
  }

  const unsigned char *kg[4], *vg[4];
  {
    const unsigned char* Ksrc = (const unsigned char*)(Kb + (long)b * CS * CE + h * CD);
    const unsigned char* Vsrc = (const unsigned char*)(Vtw + (long)(b * CH + h) * CD * CS);
    const int rr8 = lane >> 3;
    const int csw = ((lane & 7) << 4) ^ (rr8 << 4);
#pragma unroll
    for (int t = 0; t < 4; t++) {
      const int krow = t * 32 + w * 8 + rr8;
      const int key = (krow & 96) + ((krow >> 2) & 3) * 8 + ((krow >> 4) & 1) * 4 + (krow & 3);
      kg[t] = Ksrc + (long)key * (CE * 2) + csw;
      const int vrow = (t & 1) * 32 + w * 8 + rr8;
      vg[t] = Vsrc + (long)vrow * (CS * 2) + (t >> 1) * 128 + csw;
    }
  }
  const int sw = (c & 7) << 4;
  const unsigned char* rb0 = lds + c * 128 + ((g * 16) ^ sw);
  const unsigned char* rb1 = lds + c * 128 + ((64 + g * 16) ^ sw);

  const unsigned short* mbp0 = mb16 + ((long)b * CS + qbase + c) * CS + g * 8;
  const unsigned short* mbp1 = mb16 + ((long)b * CS + qbase + 16 + c) * CS + g * 8;

  f32x4 o[2][4] = {};
  f32x4 lsum4[2] = {};
  uint4 mbr[2][4];

  auto stage = [&](int bo) {
    unsigned char* kbuf = lds + bo;
    unsigned char* vbuf = lds + bo + 16384;
#pragma unroll
    for (int t = 0; t < 4; t++) {
      stage16(kg[t], kbuf + t * 4096 + w * 1024);
      stage16(vg[t], vbuf + (t >> 1) * 8192 + (t & 1) * 4096 + w * 1024);
      kg[t] += 128 * CE * 2;
      vg[t] += 128 * 2;
    }
  };
  auto load_mb = [&](bool adv) {
#pragma unroll
    for (int kb = 0; kb < 4; kb++) {
      mbr[0][kb] = *reinterpret_cast<const uint4*>(mbp0 + kb * 32);
      mbr[1][kb] = *reinterpret_cast<const uint4*>(mbp1 + kb * 32);
    }
    if (adv) { mbp0 += 128; mbp1 += 128; }
  };

  auto compute = [&](int bo, bool adv) {
    f32x4 sf[2][8];
    __builtin_amdgcn_s_setprio(1);
#pragma unroll
    for (int cb = 0; cb < 8; cb++) {
      const bf16x8 kf0 = *reinterpret_cast<const bf16x8*>(rb0 + bo + cb * 2048);
      const bf16x8 kf1 = *reinterpret_cast<const bf16x8*>(rb1 + bo + cb * 2048);
#pragma unroll
      for (int qb = 0; qb < 2; qb++) {
        const uint4 m = mbr[qb][cb >> 1];
        const f32x4 ci = (cb & 1) ? unpk(m.z, m.w) : unpk(m.x, m.y);
        f32x4 t = mfma32(kf0, qf[qb][0], ci);
        sf[qb][cb] = mfma32(kf1, qf[qb][1], t);
      }
    }
    __builtin_amdgcn_s_setprio(0);
    load_mb(adv);
    uint4 pw[2][4];
#pragma unroll
    for (int qb = 0; qb < 2; qb++)
#pragma unroll
      for (int kb = 0; kb < 4; kb++)
#pragma unroll
        for (int half = 0; half < 2; half++) {
          const int cb = 2 * kb + half;
          f32x4 pv;
          pv[0] = exp2r(sf[qb][cb][0]);
          pv[1] = exp2r(sf[qb][cb][1]);
          pv[2] = exp2r(sf[qb][cb][2]);
          pv[3] = exp2r(sf[qb][cb][3]);
          lsum4[qb] = lsum4[qb] + pv;
          if (half == 0) { pw[qb][kb].x = cvtpk(pv[0], pv[1]); pw[qb][kb].y = cvtpk(pv[2], pv[3]); }
          else           { pw[qb][kb].z = cvtpk(pv[0], pv[1]); pw[qb][kb].w = cvtpk(pv[2], pv[3]); }
        }
    __builtin_amdgcn_s_setprio(1);
#pragma unroll
    for (int nb = 0; nb < 4; nb++) {
#pragma unroll
      for (int kb = 0; kb < 4; kb++) {
        const unsigned char* rbx = (kb & 1) ? rb1 : rb0;
        const bf16x8 vf = *reinterpret_cast<const bf16x8*>(
            rbx + bo + 16384 + (kb >> 1) * 8192 + nb * 2048);
#pragma unroll
        for (int qb = 0; qb < 2; qb++)
          o[qb][nb] = mfma32(vf, __builtin_bit_cast(bf16x8, pw[qb][kb]), o[qb][nb]);
      }
    }
    __builtin_amdgcn_s_setprio(0);
  };

  stage(0);
  load_mb(true);
  stage(32768);

#pragma unroll 1
  for (int it = 0; it < 8; ++it) {
    asm volatile("s_waitcnt vmcnt(16)" ::: "memory");
    __builtin_amdgcn_s_barrier();
    __builtin_amdgcn_sched_barrier(0);
    compute(0, it < 7);
    __builtin_amdgcn_sched_barrier(0);
    __builtin_amdgcn_s_barrier();
    stage(0);
    asm volatile("s_waitcnt vmcnt(16)" ::: "memory");
    __builtin_amdgcn_s_barrier();
    __builtin_amdgcn_sched_barrier(0);
    compute(32768, it < 7);
    __builtin_amdgcn_sched_barrier(0);
    __builtin_amdgcn_s_barrier();
    stage(32768);
  }

#pragma unroll
  for (int qb = 0; qb < 2; qb++) {
    float lsum = (lsum4[qb][0] + lsum4[qb][1]) + (lsum4[qb][2] + lsum4[qb][3]);
    lsum += __shfl_xor(lsum, 16, 64);
    lsum += __shfl_xor(lsum, 32, 64);
    const float linv = 1.0f / lsum;
    unsigned short* Orow = AO + ((long)b * CS + qbase + qb * 16 + c) * CE + h * CD;
#pragma unroll
    for (int nb = 0; nb < 4; nb++) {
      uint2 val;
      val.x = (unsigned int)f2bf(o[qb][nb][0] * linv) | ((unsigned int)f2bf(o[qb][nb][1] * linv) << 16);
      val.y = (unsigned int)f2bf(o[qb][nb][2] * linv) | ((unsigned int)f2bf(o[qb][nb][3] * linv) << 16);
      *reinterpret_cast<uint2*>(Orow + nb * 16 + g * 4) = val;
    }
  }
  asm volatile("s_waitcnt vmcnt(0)" ::: "memory");
}

// ---------------- host ----------------
extern "C" void kernel_launch(void* const* d_in, const int* in_sizes, int n_in,
                              void* d_out, int out_size, void* d_ws, size_t ws_size,
                              hipStream_t stream) {
  (void)in_sizes; (void)n_in; (void)out_size; (void)ws_size;
  const float* x    = (const float*)d_in[0];
  const float* kv   = (const float*)d_in[1];
  const int*   mask = (const int*)d_in[2];
  const float* ab   = (const float*)d_in[3];
  const float* WQw  = (const float*)d_in[4];
  const float* WQb  = (const float*)d_in[5];
  const float* WKw  = (const float*)d_in[6];
  const float* WKb  = (const float*)d_in[7];
  const float* WVw  = (const float*)d_in[8];
  const float* WVb  = (const float*)d_in[9];
  const float* WOw  = (const float*)d_in[10];
  const float* WOb  = (const float*)d_in[11];
  float* out = (float*)d_out;

  const long NE = (long)CB * CS * CE;  // 4,194,304
  const long WE = (long)CE * CE;       // 1,048,576
  unsigned short* ws  = (unsigned short*)d_ws;
  unsigned short* wqb = ws;            // WQ|WK|WV contiguous = Wall
  unsigned short* wob = wqb + 3 * WE;
  unsigned short* Qb  = wob + WE;      // Q | K | Vt | AO contiguous
  unsigned short* AO  = Qb + 3 * NE;
  unsigned short* mb16 = AO + NE;      // CB*CS*CS bf16; total ws use = 58.7 MB

  const long WCE = 4 * WE;             // weight cvt elements
  const long MBE = (long)CB * CS * CS; // mbias elements

  prep_all<<<(int)((WCE + MBE) / 2048), 256, 0, stream>>>(WQw, WKw, WVw, WOw, wqb,
                                                          ab, mask, mb16);

  gemm_qkv<<<dim3(16, 12), 512, 0, stream>>>(x, kv, wqb, WQb, WKb, WVb, Qb);

  attn_kernel<<<dim3(CH, CS / 128, CB), 256, 0, stream>>>(
      Qb, Qb + NE, Qb + 2 * NE, mb16, mask, AO);

  gemm_wo<<<dim3(32, 16), 256, 0, stream>>>(AO, wob, WOb, out);
}

// Round 22
// 128.705 us; speedup vs baseline: 1.4912x; 1.0268x over previous
//
#include <hip/hip_runtime.h>

#define DEV static __device__ __forceinline__

typedef __attribute__((ext_vector_type(8))) __bf16 bf16x8;
typedef __attribute__((ext_vector_type(4))) float f32x4;

constexpr int CB = 2;     // batch
constexpr int CS = 2048;  // seq
constexpr int CE = 1024;  // embed
constexpr int CH = 16;    // heads
constexpr int CD = 64;    // head dim
constexpr float LOG2E = 1.44269504f;

DEV unsigned short f2bf(float x) {  // RNE f32 -> bf16 bits
  unsigned int u = __float_as_uint(x);
  u += 0x7fffu + ((u >> 16) & 1u);
  return (unsigned short)(u >> 16);
}

DEV f32x4 mfma32(bf16x8 a, bf16x8 b, f32x4 c) {  // 16x16x32
  return __builtin_amdgcn_mfma_f32_16x16x32_bf16(a, b, c, 0, 0, 0);
}

DEV unsigned int cvtpk(float lo, float hi) {  // pack 2 f32 -> 2 bf16 (RNE)
  unsigned int r;
  asm("v_cvt_pk_bf16_f32 %0, %1, %2" : "=v"(r) : "v"(lo), "v"(hi));
  return r;
}

DEV float exp2r(float x) {  // raw v_exp_f32
#if __has_builtin(__builtin_amdgcn_exp2f)
  return __builtin_amdgcn_exp2f(x);
#else
  float r; asm("v_exp_f32 %0, %1" : "=v"(r) : "v"(x)); return r;
#endif
}

DEV f32x4 unpk(unsigned int a, unsigned int b) {  // 4 packed bf16 -> f32x4
  f32x4 r;
  r[0] = __uint_as_float(a << 16);
  r[1] = __uint_as_float(a & 0xffff0000u);
  r[2] = __uint_as_float(b << 16);
  r[3] = __uint_as_float(b & 0xffff0000u);
  return r;
}

DEV void stage16(const void* g, void* l) {  // async global(16B/lane) -> LDS
  __builtin_amdgcn_global_load_lds(
      (const __attribute__((address_space(1))) unsigned int*)g,
      (__attribute__((address_space(3))) unsigned int*)l, 16, 0, 0);
}

// ---- prep: weight f32->bf16 only (mbias fused into gemm_qkv launch) ----
__global__ __launch_bounds__(256) void wcvt_all(const float* __restrict__ w0,
                                                const float* __restrict__ w1,
                                                const float* __restrict__ w2,
                                                const float* __restrict__ w3,
                                                unsigned short* __restrict__ out) {
  const long WE = (long)CE * CE;
  const long i = ((long)blockIdx.x * 256 + threadIdx.x) * 8;
  const int wi = (int)(i >> 20);
  const float* src = wi == 0 ? w0 : wi == 1 ? w1 : wi == 2 ? w2 : w3;
  const long off = i & (WE - 1);
  float4 a = *reinterpret_cast<const float4*>(src + off);
  float4 b = *reinterpret_cast<const float4*>(src + off + 4);
  uint4 v;
  v.x = cvtpk(a.x, a.y); v.y = cvtpk(a.z, a.w);
  v.z = cvtpk(b.x, b.y); v.w = cvtpk(b.z, b.w);
  *reinterpret_cast<uint4*>(out + i) = v;
}

// mbias (bf16, log2 domain): mq==0 -> 0 ; mq&&mk==0 -> -1e9*log2e ; else bias*log2e
DEV void mbias_body512(long idx, const float* __restrict__ bias, const int* __restrict__ mask,
                       unsigned short* __restrict__ mb16) {
  const int b = (int)(idx >> 22);
  const int q = (int)((idx >> 11) & (CS - 1));
  const int k0 = (int)(idx & (CS - 1));
  const bool mq = mask[b * CS + q] != 0;
  const int4 mk0 = *reinterpret_cast<const int4*>(mask + b * CS + k0);
  const int4 mk1 = *reinterpret_cast<const int4*>(mask + b * CS + k0 + 4);
  const float4 b0 = *reinterpret_cast<const float4*>(bias + idx);
  const float4 b1 = *reinterpret_cast<const float4*>(bias + idx + 4);
  const float NEG = -1e9f * LOG2E;
  float v[8];
  if (mq) {
    v[0] = (mk0.x != 0) ? b0.x * LOG2E : NEG;
    v[1] = (mk0.y != 0) ? b0.y * LOG2E : NEG;
    v[2] = (mk0.z != 0) ? b0.z * LOG2E : NEG;
    v[3] = (mk0.w != 0) ? b0.w * LOG2E : NEG;
    v[4] = (mk1.x != 0) ? b1.x * LOG2E : NEG;
    v[5] = (mk1.y != 0) ? b1.y * LOG2E : NEG;
    v[6] = (mk1.z != 0) ? b1.z * LOG2E : NEG;
    v[7] = (mk1.w != 0) ? b1.w * LOG2E : NEG;
  } else {
#pragma unroll
    for (int j = 0; j < 8; j++) v[j] = 0.f;  // uniform row (qf also zeroed in attn)
  }
  uint4 o;
  o.x = cvtpk(v[0], v[1]); o.y = cvtpk(v[2], v[3]);
  o.z = cvtpk(v[4], v[5]); o.w = cvtpk(v[6], v[7]);
  *reinterpret_cast<uint4*>(mb16 + idx) = o;
}

// ---------------- QKV GEMM v7: 256x256/BK=32 pipelined + mbias side-blocks ----------------
// 1D grid: blocks [0,192) = GEMM tiles (mx = bx&15, ny = bx>>4); blocks [192,2240) = mbias
// (512 thr x 8 elems, fills CUs left idle by the 192-block GEMM). GEMM path = R21 v6.
__global__ __launch_bounds__(512) void gemm_qkv(const float* __restrict__ xf,
                                                const float* __restrict__ kvf,
                                                const unsigned short* __restrict__ Wall,
                                                const float* __restrict__ bq,
                                                const float* __restrict__ bk,
                                                const float* __restrict__ bv,
                                                unsigned short* __restrict__ Qb,
                                                const float* __restrict__ bias,
                                                const int* __restrict__ mask,
                                                unsigned short* __restrict__ mb16) {
  __shared__ __align__(16) unsigned char ldsA[32768];  // 2 x 16KB
  __shared__ __align__(16) unsigned char ldsB[32768];
  const int bx = blockIdx.x;
  const int tid = threadIdx.x;
  if (bx >= 192) {  // ---- mbias side-block ----
    mbias_body512(((long)(bx - 192) * 512 + tid) * 8, bias, mask, mb16);
    return;
  }
  const long NE = (long)CB * CS * CE;
  const long WE = (long)CE * CE;
  const int mx = bx & 15, ny = bx >> 4;
  const int which = ny >> 2;                  // 0=Q 1=K 2=V
  const int n0 = (ny & 3) * 256;
  const int m0 = mx * 256;
  const float* Ax = which == 0 ? xf : kvf;
  const unsigned char* Bb = (const unsigned char*)(Wall + (long)which * WE);
  const float* bq_ = which == 0 ? bq : which == 1 ? bk : bv;

  const int lane = tid & 63, w = tid >> 6;
  const int wr = w >> 2, wc = w & 3;
  const int g = lane >> 4, rr = lane & 15;

  const int srow = tid >> 2;                                    // 0..127
  const int ecol = ((tid & 3) * 8) ^ (((tid >> 5) & 1) * 16);   // swizzled elem col
  const float* afp0 = Ax + (long)(m0 + srow) * CE + ecol;
  const float* afp1 = Ax + (long)(m0 + 128 + srow) * CE + ecol;
  const float* afb0 = afp0;  // clamped junk sources (stay in-bounds)
  const float* afb1 = afp1;
  const int scsw = ((tid & 3) * 16) ^ (((tid >> 5) & 1) << 5);
  const unsigned char* bpR0 = Bb + ((long)(n0 + srow) * CE) * 2 + scsw;
  const unsigned char* bpR1 = Bb + ((long)(n0 + 128 + srow) * CE) * 2 + scsw;

  const int cswz = (g * 16) ^ (((rr >> 3) & 1) << 5);
  const unsigned char* rbA = ldsA + wr * 8192 + rr * 64 + cswz;
  const unsigned char* rbB = ldsB + wc * 4096 + rr * 64 + cswz;

  f32x4 acc[8][4] = {};
  float4 afr0, afr1, afr2, afr3;

  auto loadA = [&](bool junk) {
    const float* p0 = junk ? afb0 : afp0;
    const float* p1 = junk ? afb1 : afp1;
    afr0 = *reinterpret_cast<const float4*>(p0);
    afr1 = *reinterpret_cast<const float4*>(p0 + 4);
    afr2 = *reinterpret_cast<const float4*>(p1);
    afr3 = *reinterpret_cast<const float4*>(p1 + 4);
    if (!junk) { afp0 += 32; afp1 += 32; }
  };
  auto writeA = [&](int buf) {
    uint4 w0v, w1v;
    w0v.x = cvtpk(afr0.x, afr0.y); w0v.y = cvtpk(afr0.z, afr0.w);
    w0v.z = cvtpk(afr1.x, afr1.y); w0v.w = cvtpk(afr1.z, afr1.w);
    w1v.x = cvtpk(afr2.x, afr2.y); w1v.y = cvtpk(afr2.z, afr2.w);
    w1v.z = cvtpk(afr3.x, afr3.y); w1v.w = cvtpk(afr3.z, afr3.w);
    *reinterpret_cast<uint4*>(ldsA + buf * 16384 + tid * 16) = w0v;
    *reinterpret_cast<uint4*>(ldsA + buf * 16384 + 8192 + tid * 16) = w1v;
  };
  auto stB = [&](int buf) {
    stage16(bpR0, ldsB + buf * 16384 + w * 1024);
    stage16(bpR1, ldsB + buf * 16384 + 8192 + w * 1024);
    bpR0 += 64; bpR1 += 64;
  };

  // prologue -> establish entry invariant: outstanding = [Af(1):4][B(1):2]
  loadA(false);
  stB(0);
  asm volatile("s_waitcnt vmcnt(2)" ::: "memory");
  writeA(0);
  loadA(false);
  stB(1);
  asm volatile("s_waitcnt vmcnt(6)" ::: "memory");
  asm volatile("s_waitcnt lgkmcnt(0)" ::: "memory");
  __builtin_amdgcn_s_barrier();

  auto group = [&](int buf, bool junk) {
    bf16x8 ar[4], br[4];
#pragma unroll
    for (int ii = 0; ii < 4; ii++)
      ar[ii] = *reinterpret_cast<const bf16x8*>(rbA + buf * 16384 + ii * 1024);
#pragma unroll
    for (int j = 0; j < 4; j++)
      br[j] = *reinterpret_cast<const bf16x8*>(rbB + buf * 16384 + j * 1024);
    asm volatile("s_waitcnt vmcnt(2)" ::: "memory");  // Af(t+1) regs landed
    writeA(buf ^ 1);
    loadA(junk);
    asm volatile("s_waitcnt lgkmcnt(0)" ::: "memory");
    __builtin_amdgcn_sched_barrier(0);
    __builtin_amdgcn_s_setprio(1);
#pragma unroll
    for (int ii = 0; ii < 4; ii++)
#pragma unroll
      for (int j = 0; j < 4; j++)
        acc[ii][j] = mfma32(ar[ii], br[j], acc[ii][j]);
    __builtin_amdgcn_s_setprio(0);
    __builtin_amdgcn_s_barrier();                     // close phase 0
#pragma unroll
    for (int ii = 0; ii < 4; ii++)
      ar[ii] = *reinterpret_cast<const bf16x8*>(rbA + buf * 16384 + 4096 + ii * 1024);
    stB(buf);
    asm volatile("s_waitcnt lgkmcnt(0)" ::: "memory");
    __builtin_amdgcn_sched_barrier(0);
    __builtin_amdgcn_s_setprio(1);
#pragma unroll
    for (int ii = 0; ii < 4; ii++)
#pragma unroll
      for (int j = 0; j < 4; j++)
        acc[4 + ii][j] = mfma32(ar[ii], br[j], acc[4 + ii][j]);
    __builtin_amdgcn_s_setprio(0);
    asm volatile("s_waitcnt vmcnt(6)" ::: "memory");  // B(t+1) landed
    __builtin_amdgcn_s_barrier();                     // close phase 1
  };

#pragma unroll 1
  for (int it = 0; it < 16; ++it) {  // 32 K-tiles of 32
    group(0, it == 15);
    group(1, it == 15);
  }
  asm volatile("s_waitcnt vmcnt(0)" ::: "memory");

  const float scale = which == 0 ? 0.125f * LOG2E : 1.0f;
#pragma unroll
  for (int i = 0; i < 8; i++) {
#pragma unroll
    for (int j = 0; j < 4; j++) {
      const int colg = n0 + wc * 64 + j * 16 + rr;
      const float bvv = bq_[colg];
      if (which == 2) {  // V^T layout [B,H,DK,S]
        const int rowbase = m0 + wr * 128 + i * 16 + g * 4;
        const int bb = rowbase >> 11, s = rowbase & 2047;
        const int hh = colg >> 6, d = colg & 63;
        uint2 val;
        val.x = (unsigned int)f2bf(acc[i][j][0] + bvv) | ((unsigned int)f2bf(acc[i][j][1] + bvv) << 16);
        val.y = (unsigned int)f2bf(acc[i][j][2] + bvv) | ((unsigned int)f2bf(acc[i][j][3] + bvv) << 16);
        *reinterpret_cast<uint2*>(Qb + 2 * NE + ((long)((bb * CH + hh) * CD + d)) * CS + s) = val;
      } else {
        unsigned short* outp = Qb + (long)which * NE;
#pragma unroll
        for (int r = 0; r < 4; r++) {
          const int row = m0 + wr * 128 + i * 16 + g * 4 + r;
          outp[(long)row * CE + colg] = f2bf((acc[i][j][r] + bvv) * scale);
        }
      }
    }
  }
}

// ---------------- WO GEMM: 128x64 tile, 512 blocks (2/CU) ----------------
__global__ __launch_bounds__(256) void gemm_wo(const unsigned short* __restrict__ A,
                                               const unsigned short* __restrict__ W,
                                               const float* __restrict__ bias,
                                               float* __restrict__ out) {
  __shared__ __align__(16) unsigned short As[128 * 64];
  __shared__ __align__(16) unsigned short Bs[64 * 64];
  const int tid = threadIdx.x;
  const int lane = tid & 63, wave = tid >> 6;
  const int wm = (wave >> 1) * 64, wn = (wave & 1) * 32;
  const int g = lane >> 4, rr = lane & 15;
  const int m0 = blockIdx.x * 128, n0 = blockIdx.y * 64;
  const int K = CE;
  f32x4 acc[4][2] = {};

  for (int k0 = 0; k0 < K; k0 += 64) {
#pragma unroll
    for (int t = 0; t < 4; t++) {
      const int u = t * 256 + tid;
      const int row = u >> 3, ce = (u & 7) * 8;
      stage16(A + (long)(m0 + row) * K + k0 + ce, (char*)As + (t * 256 + (tid & 192)) * 16);
    }
#pragma unroll
    for (int t = 0; t < 2; t++) {
      const int u = t * 256 + tid;
      const int row = u >> 3, ce = (u & 7) * 8;
      stage16(W + (long)(n0 + row) * K + k0 + ce, (char*)Bs + (t * 256 + (tid & 192)) * 16);
    }
    __syncthreads();
#pragma unroll
    for (int kk = 0; kk < 2; kk++) {
      bf16x8 af[4], bfr[2];
#pragma unroll
      for (int i = 0; i < 4; i++)
        af[i] = *reinterpret_cast<const bf16x8*>(&As[(wm + i * 16 + rr) * 64 + kk * 32 + g * 8]);
#pragma unroll
      for (int j = 0; j < 2; j++)
        bfr[j] = *reinterpret_cast<const bf16x8*>(&Bs[(wn + j * 16 + rr) * 64 + kk * 32 + g * 8]);
#pragma unroll
      for (int i = 0; i < 4; i++)
#pragma unroll
        for (int j = 0; j < 2; j++)
          acc[i][j] = mfma32(af[i], bfr[j], acc[i][j]);
    }
    __syncthreads();
  }

#pragma unroll
  for (int i = 0; i < 4; i++)
#pragma unroll
    for (int j = 0; j < 2; j++) {
      const int colg = n0 + wn + j * 16 + rr;
      const float bvv = bias[colg];
#pragma unroll
      for (int r = 0; r < 4; r++) {
        const int row = m0 + wm + i * 16 + g * 4 + r;
        out[(long)row * CE + colg] = acc[i][j][r] + bvv;
      }
    }
}

// ---------------- Flash attention: BK=128, static softmax, mb16 precomputed ----------------
__global__ __launch_bounds__(256, 2) void attn_kernel(const unsigned short* __restrict__ Qb,
                                                      const unsigned short* __restrict__ Kb,
                                                      const unsigned short* __restrict__ Vtw,
                                                      const unsigned short* __restrict__ mb16,
                                                      const int* __restrict__ mask,
                                                      unsigned short* __restrict__ AO) {
  __shared__ __align__(16) unsigned char lds[65536];
  const int h = blockIdx.x, qt = blockIdx.y, b = blockIdx.z;
  const int tid = threadIdx.x;
  const int lane = tid & 63, w = tid >> 6;
  const int g = lane >> 4, c = lane & 15;
  const int qbase = qt * 128 + w * 32;

  bf16x8 qf[2][2];
#pragma unroll
  for (int qb = 0; qb < 2; qb++) {
    const unsigned short* Qrow = Qb + ((long)b * CS + qbase + qb * 16 + c) * CE + h * CD;
    qf[qb][0] = *reinterpret_cast<const bf16x8*>(Qrow + g * 8);
    qf[qb][1] = *reinterpret_cast<const bf16x8*>(Qrow + 32 + g * 8);
    if (mask[b * CS + qbase + qb * 16 + c] == 0) {
      qf[qb][0] = bf16x8{}; qf[qb][1] = bf16x8{};
    }
  }

  const unsigned char *kg[4], *vg[4];
  {
    const unsigned char* Ksrc = (const unsigned char*)(Kb + (long)b * CS * CE + h * CD);
    const unsigned char* Vsrc = (const unsigned char*)(Vtw + (long)(b * CH + h) * CD * CS);
    const int rr8 = lane >> 3;
    const int csw = ((lane & 7) << 4) ^ (rr8 << 4);
#pragma unroll
    for (int t = 0; t < 4; t++) {
      const int krow = t * 32 + w * 8 + rr8;
      const int key = (krow & 96) + ((krow >> 2) & 3) * 8 + ((krow >> 4) & 1) * 4 + (krow & 3);
      kg[t] = Ksrc + (long)key * (CE * 2) + csw;
      const int vrow = (t & 1) * 32 + w * 8 + rr8;
      vg[t] = Vsrc + (long)vrow * (CS * 2) + (t >> 1) * 128 + csw;
    }
  }
  const int sw = (c & 7) << 4;
  const unsigned char* rb0 = lds + c * 128 + ((g * 16) ^ sw);
  const unsigned char* rb1 = lds + c * 128 + ((64 + g * 16) ^ sw);

  const unsigned short* mbp0 = mb16 + ((long)b * CS + qbase + c) * CS + g * 8;
  const unsigned short* mbp1 = mb16 + ((long)b * CS + qbase + 16 + c) * CS + g * 8;

  f32x4 o[2][4] = {};
  f32x4 lsum4[2] = {};
  uint4 mbr[2][4];

  auto stage = [&](int bo) {
    unsigned char* kbuf = lds + bo;
    unsigned char* vbuf = lds + bo + 16384;
#pragma unroll
    for (int t = 0; t < 4; t++) {
      stage16(kg[t], kbuf + t * 4096 + w * 1024);
      stage16(vg[t], vbuf + (t >> 1) * 8192 + (t & 1) * 4096 + w * 1024);
      kg[t] += 128 * CE * 2;
      vg[t] += 128 * 2;
    }
  };
  auto load_mb = [&](bool adv) {
#pragma unroll
    for (int kb = 0; kb < 4; kb++) {
      mbr[0][kb] = *reinterpret_cast<const uint4*>(mbp0 + kb * 32);
      mbr[1][kb] = *reinterpret_cast<const uint4*>(mbp1 + kb * 32);
    }
    if (adv) { mbp0 += 128; mbp1 += 128; }
  };

  auto compute = [&](int bo, bool adv) {
    f32x4 sf[2][8];
    __builtin_amdgcn_s_setprio(1);
#pragma unroll
    for (int cb = 0; cb < 8; cb++) {
      const bf16x8 kf0 = *reinterpret_cast<const bf16x8*>(rb0 + bo + cb * 2048);
      const bf16x8 kf1 = *reinterpret_cast<const bf16x8*>(rb1 + bo + cb * 2048);
#pragma unroll
      for (int qb = 0; qb < 2; qb++) {
        const uint4 m = mbr[qb][cb >> 1];
        const f32x4 ci = (cb & 1) ? unpk(m.z, m.w) : unpk(m.x, m.y);
        f32x4 t = mfma32(kf0, qf[qb][0], ci);
        sf[qb][cb] = mfma32(kf1, qf[qb][1], t);
      }
    }
    __builtin_amdgcn_s_setprio(0);
    load_mb(adv);
    uint4 pw[2][4];
#pragma unroll
    for (int qb = 0; qb < 2; qb++)
#pragma unroll
      for (int kb = 0; kb < 4; kb++)
#pragma unroll
        for (int half = 0; half < 2; half++) {
          const int cb = 2 * kb + half;
          f32x4 pv;
          pv[0] = exp2r(sf[qb][cb][0]);
          pv[1] = exp2r(sf[qb][cb][1]);
          pv[2] = exp2r(sf[qb][cb][2]);
          pv[3] = exp2r(sf[qb][cb][3]);
          lsum4[qb] = lsum4[qb] + pv;
          if (half == 0) { pw[qb][kb].x = cvtpk(pv[0], pv[1]); pw[qb][kb].y = cvtpk(pv[2], pv[3]); }
          else           { pw[qb][kb].z = cvtpk(pv[0], pv[1]); pw[qb][kb].w = cvtpk(pv[2], pv[3]); }
        }
    __builtin_amdgcn_s_setprio(1);
#pragma unroll
    for (int nb = 0; nb < 4; nb++) {
#pragma unroll
      for (int kb = 0; kb < 4; kb++) {
        const unsigned char* rbx = (kb & 1) ? rb1 : rb0;
        const bf16x8 vf = *reinterpret_cast<const bf16x8*>(
            rbx + bo + 16384 + (kb >> 1) * 8192 + nb * 2048);
#pragma unroll
        for (int qb = 0; qb < 2; qb++)
          o[qb][nb] = mfma32(vf, __builtin_bit_cast(bf16x8, pw[qb][kb]), o[qb][nb]);
      }
    }
    __builtin_amdgcn_s_setprio(0);
  };

  stage(0);
  load_mb(true);
  stage(32768);

#pragma unroll 1
  for (int it = 0; it < 8; ++it) {
    asm volatile("s_waitcnt vmcnt(16)" ::: "memory");
    __builtin_amdgcn_s_barrier();
    __builtin_amdgcn_sched_barrier(0);
    compute(0, it < 7);
    __builtin_amdgcn_sched_barrier(0);
    __builtin_amdgcn_s_barrier();
    stage(0);
    asm volatile("s_waitcnt vmcnt(16)" ::: "memory");
    __builtin_amdgcn_s_barrier();
    __builtin_amdgcn_sched_barrier(0);
    compute(32768, it < 7);
    __builtin_amdgcn_sched_barrier(0);
    __builtin_amdgcn_s_barrier();
    stage(32768);
  }

#pragma unroll
  for (int qb = 0; qb < 2; qb++) {
    float lsum = (lsum4[qb][0] + lsum4[qb][1]) + (lsum4[qb][2] + lsum4[qb][3]);
    lsum += __shfl_xor(lsum, 16, 64);
    lsum += __shfl_xor(lsum, 32, 64);
    const float linv = 1.0f / lsum;
    unsigned short* Orow = AO + ((long)b * CS + qbase + qb * 16 + c) * CE + h * CD;
#pragma unroll
    for (int nb = 0; nb < 4; nb++) {
      uint2 val;
      val.x = (unsigned int)f2bf(o[qb][nb][0] * linv) | ((unsigned int)f2bf(o[qb][nb][1] * linv) << 16);
      val.y = (unsigned int)f2bf(o[qb][nb][2] * linv) | ((unsigned int)f2bf(o[qb][nb][3] * linv) << 16);
      *reinterpret_cast<uint2*>(Orow + nb * 16 + g * 4) = val;
    }
  }
  asm volatile("s_waitcnt vmcnt(0)" ::: "memory");
}

// ---------------- host ----------------
extern "C" void kernel_launch(void* const* d_in, const int* in_sizes, int n_in,
                              void* d_out, int out_size, void* d_ws, size_t ws_size,
                              hipStream_t stream) {
  (void)in_sizes; (void)n_in; (void)out_size; (void)ws_size;
  const float* x    = (const float*)d_in[0];
  const float* kv   = (const float*)d_in[1];
  const int*   mask = (const int*)d_in[2];
  const float* ab   = (const float*)d_in[3];
  const float* WQw  = (const float*)d_in[4];
  const float* WQb  = (const float*)d_in[5];
  const float* WKw  = (const float*)d_in[6];
  const float* WKb  = (const float*)d_in[7];
  const float* WVw  = (const float*)d_in[8];
  const float* WVb  = (const float*)d_in[9];
  const float* WOw  = (const float*)d_in[10];
  const float* WOb  = (const float*)d_in[11];
  float* out = (float*)d_out;

  const long NE = (long)CB * CS * CE;  // 4,194,304
  const long WE = (long)CE * CE;       // 1,048,576
  unsigned short* ws  = (unsigned short*)d_ws;
  unsigned short* wqb = ws;            // WQ|WK|WV contiguous = Wall
  unsigned short* wob = wqb + 3 * WE;
  unsigned short* Qb  = wob + WE;      // Q | K | Vt | AO contiguous
  unsigned short* AO  = Qb + 3 * NE;
  unsigned short* mb16 = AO + NE;      // CB*CS*CS bf16; total ws use = 58.7 MB

  wcvt_all<<<(int)((4 * WE) / 2048), 256, 0, stream>>>(WQw, WKw, WVw, WOw, wqb);

  // GEMM (192 blocks) + mbias (2048 blocks) fused: mbias fills idle CUs during GEMM
  gemm_qkv<<<dim3(192 + 2048), 512, 0, stream>>>(x, kv, wqb, WQb, WKb, WVb, Qb,
                                                 ab, mask, mb16);

  attn_kernel<<<dim3(CH, CS / 128, CB), 256, 0, stream>>>(
      Qb, Qb + NE, Qb + 2 * NE, mb16, mask, AO);

  gemm_wo<<<dim3(32, 16), 256, 0, stream>>>(AO, wob, WOb, out);
}

// Round 23
// 128.552 us; speedup vs baseline: 1.4930x; 1.0012x over previous
//
#include <hip/hip_runtime.h>

#define DEV static __device__ __forceinline__

typedef __attribute__((ext_vector_type(8))) __bf16 bf16x8;
typedef __attribute__((ext_vector_type(4))) float f32x4;

constexpr int CB = 2;     // batch
constexpr int CS = 2048;  // seq
constexpr int CE = 1024;  // embed
constexpr int CH = 16;    // heads
constexpr int CD = 64;    // head dim
constexpr float LOG2E = 1.44269504f;

DEV unsigned short f2bf(float x) {  // RNE f32 -> bf16 bits
  unsigned int u = __float_as_uint(x);
  u += 0x7fffu + ((u >> 16) & 1u);
  return (unsigned short)(u >> 16);
}

DEV f32x4 mfma32(bf16x8 a, bf16x8 b, f32x4 c) {  // 16x16x32
  return __builtin_amdgcn_mfma_f32_16x16x32_bf16(a, b, c, 0, 0, 0);
}

DEV unsigned int cvtpk(float lo, float hi) {  // pack 2 f32 -> 2 bf16 (RNE)
  unsigned int r;
  asm("v_cvt_pk_bf16_f32 %0, %1, %2" : "=v"(r) : "v"(lo), "v"(hi));
  return r;
}

DEV float exp2r(float x) {  // raw v_exp_f32
#if __has_builtin(__builtin_amdgcn_exp2f)
  return __builtin_amdgcn_exp2f(x);
#else
  float r; asm("v_exp_f32 %0, %1" : "=v"(r) : "v"(x)); return r;
#endif
}

DEV f32x4 unpk(unsigned int a, unsigned int b) {  // 4 packed bf16 -> f32x4
  f32x4 r;
  r[0] = __uint_as_float(a << 16);
  r[1] = __uint_as_float(a & 0xffff0000u);
  r[2] = __uint_as_float(b << 16);
  r[3] = __uint_as_float(b & 0xffff0000u);
  return r;
}

DEV void stage16(const void* g, void* l) {  // async global(16B/lane) -> LDS
  __builtin_amdgcn_global_load_lds(
      (const __attribute__((address_space(1))) unsigned int*)g,
      (__attribute__((address_space(3))) unsigned int*)l, 16, 0, 0);
}

// ---- prep: weight f32->bf16 only (mbias fused into gemm_qkv launch) ----
__global__ __launch_bounds__(256) void wcvt_all(const float* __restrict__ w0,
                                                const float* __restrict__ w1,
                                                const float* __restrict__ w2,
                                                const float* __restrict__ w3,
                                                unsigned short* __restrict__ out) {
  const long WE = (long)CE * CE;
  const long i = ((long)blockIdx.x * 256 + threadIdx.x) * 8;
  const int wi = (int)(i >> 20);
  const float* src = wi == 0 ? w0 : wi == 1 ? w1 : wi == 2 ? w2 : w3;
  const long off = i & (WE - 1);
  float4 a = *reinterpret_cast<const float4*>(src + off);
  float4 b = *reinterpret_cast<const float4*>(src + off + 4);
  uint4 v;
  v.x = cvtpk(a.x, a.y); v.y = cvtpk(a.z, a.w);
  v.z = cvtpk(b.x, b.y); v.w = cvtpk(b.z, b.w);
  *reinterpret_cast<uint4*>(out + i) = v;
}

// mbias (bf16, log2 domain): mq==0 -> 0 ; mq&&mk==0 -> -1e9*log2e ; else bias*log2e
DEV void mbias_body512(long idx, const float* __restrict__ bias, const int* __restrict__ mask,
                       unsigned short* __restrict__ mb16) {
  const int b = (int)(idx >> 22);
  const int q = (int)((idx >> 11) & (CS - 1));
  const int k0 = (int)(idx & (CS - 1));
  const bool mq = mask[b * CS + q] != 0;
  const int4 mk0 = *reinterpret_cast<const int4*>(mask + b * CS + k0);
  const int4 mk1 = *reinterpret_cast<const int4*>(mask + b * CS + k0 + 4);
  const float4 b0 = *reinterpret_cast<const float4*>(bias + idx);
  const float4 b1 = *reinterpret_cast<const float4*>(bias + idx + 4);
  const float NEG = -1e9f * LOG2E;
  float v[8];
  if (mq) {
    v[0] = (mk0.x != 0) ? b0.x * LOG2E : NEG;
    v[1] = (mk0.y != 0) ? b0.y * LOG2E : NEG;
    v[2] = (mk0.z != 0) ? b0.z * LOG2E : NEG;
    v[3] = (mk0.w != 0) ? b0.w * LOG2E : NEG;
    v[4] = (mk1.x != 0) ? b1.x * LOG2E : NEG;
    v[5] = (mk1.y != 0) ? b1.y * LOG2E : NEG;
    v[6] = (mk1.z != 0) ? b1.z * LOG2E : NEG;
    v[7] = (mk1.w != 0) ? b1.w * LOG2E : NEG;
  } else {
#pragma unroll
    for (int j = 0; j < 8; j++) v[j] = 0.f;  // uniform row (qf also zeroed in attn)
  }
  uint4 o;
  o.x = cvtpk(v[0], v[1]); o.y = cvtpk(v[2], v[3]);
  o.z = cvtpk(v[4], v[5]); o.w = cvtpk(v[6], v[7]);
  *reinterpret_cast<uint4*>(mb16 + idx) = o;
}

// ---------------- QKV GEMM v8: 256x256/BK=32 pipelined + grid-strided mbias side-blocks ----
// 1D grid: blocks [0,192) = GEMM tiles; blocks [192,448) = mbias, each doing 8 strided
// iterations (512 thr x 8 elems x 8 it) -> all side-blocks start immediately in free CU
// slots and finish inside the GEMM shadow. GEMM path = R21 v6 (unchanged).
__global__ __launch_bounds__(512) void gemm_qkv(const float* __restrict__ xf,
                                                const float* __restrict__ kvf,
                                                const unsigned short* __restrict__ Wall,
                                                const float* __restrict__ bq,
                                                const float* __restrict__ bk,
                                                const float* __restrict__ bv,
                                                unsigned short* __restrict__ Qb,
                                                const float* __restrict__ bias,
                                                const int* __restrict__ mask,
                                                unsigned short* __restrict__ mb16) {
  __shared__ __align__(16) unsigned char ldsA[32768];  // 2 x 16KB
  __shared__ __align__(16) unsigned char ldsB[32768];
  const int bx = blockIdx.x;
  const int tid = threadIdx.x;
  if (bx >= 192) {  // ---- mbias side-block: 8 grid-strided iterations ----
    const long base = ((long)(bx - 192) * 512 + tid) * 8;
    const long stride = 256L * 512 * 8;  // 1,048,576 elems per round
#pragma unroll
    for (int itr = 0; itr < 8; itr++)
      mbias_body512(base + (long)itr * stride, bias, mask, mb16);
    return;
  }
  const long NE = (long)CB * CS * CE;
  const long WE = (long)CE * CE;
  const int mx = bx & 15, ny = bx >> 4;
  const int which = ny >> 2;                  // 0=Q 1=K 2=V
  const int n0 = (ny & 3) * 256;
  const int m0 = mx * 256;
  const float* Ax = which == 0 ? xf : kvf;
  const unsigned char* Bb = (const unsigned char*)(Wall + (long)which * WE);
  const float* bq_ = which == 0 ? bq : which == 1 ? bk : bv;

  const int lane = tid & 63, w = tid >> 6;
  const int wr = w >> 2, wc = w & 3;
  const int g = lane >> 4, rr = lane & 15;

  const int srow = tid >> 2;                                    // 0..127
  const int ecol = ((tid & 3) * 8) ^ (((tid >> 5) & 1) * 16);   // swizzled elem col
  const float* afp0 = Ax + (long)(m0 + srow) * CE + ecol;
  const float* afp1 = Ax + (long)(m0 + 128 + srow) * CE + ecol;
  const float* afb0 = afp0;  // clamped junk sources (stay in-bounds)
  const float* afb1 = afp1;
  const int scsw = ((tid & 3) * 16) ^ (((tid >> 5) & 1) << 5);
  const unsigned char* bpR0 = Bb + ((long)(n0 + srow) * CE) * 2 + scsw;
  const unsigned char* bpR1 = Bb + ((long)(n0 + 128 + srow) * CE) * 2 + scsw;

  const int cswz = (g * 16) ^ (((rr >> 3) & 1) << 5);
  const unsigned char* rbA = ldsA + wr * 8192 + rr * 64 + cswz;
  const unsigned char* rbB = ldsB + wc * 4096 + rr * 64 + cswz;

  f32x4 acc[8][4] = {};
  float4 afr0, afr1, afr2, afr3;

  auto loadA = [&](bool junk) {
    const float* p0 = junk ? afb0 : afp0;
    const float* p1 = junk ? afb1 : afp1;
    afr0 = *reinterpret_cast<const float4*>(p0);
    afr1 = *reinterpret_cast<const float4*>(p0 + 4);
    afr2 = *reinterpret_cast<const float4*>(p1);
    afr3 = *reinterpret_cast<const float4*>(p1 + 4);
    if (!junk) { afp0 += 32; afp1 += 32; }
  };
  auto writeA = [&](int buf) {
    uint4 w0v, w1v;
    w0v.x = cvtpk(afr0.x, afr0.y); w0v.y = cvtpk(afr0.z, afr0.w);
    w0v.z = cvtpk(afr1.x, afr1.y); w0v.w = cvtpk(afr1.z, afr1.w);
    w1v.x = cvtpk(afr2.x, afr2.y); w1v.y = cvtpk(afr2.z, afr2.w);
    w1v.z = cvtpk(afr3.x, afr3.y); w1v.w = cvtpk(afr3.z, afr3.w);
    *reinterpret_cast<uint4*>(ldsA + buf * 16384 + tid * 16) = w0v;
    *reinterpret_cast<uint4*>(ldsA + buf * 16384 + 8192 + tid * 16) = w1v;
  };
  auto stB = [&](int buf) {
    stage16(bpR0, ldsB + buf * 16384 + w * 1024);
    stage16(bpR1, ldsB + buf * 16384 + 8192 + w * 1024);
    bpR0 += 64; bpR1 += 64;
  };

  // prologue -> establish entry invariant: outstanding = [Af(1):4][B(1):2]
  loadA(false);
  stB(0);
  asm volatile("s_waitcnt vmcnt(2)" ::: "memory");
  writeA(0);
  loadA(false);
  stB(1);
  asm volatile("s_waitcnt vmcnt(6)" ::: "memory");
  asm volatile("s_waitcnt lgkmcnt(0)" ::: "memory");
  __builtin_amdgcn_s_barrier();

  auto group = [&](int buf, bool junk) {
    bf16x8 ar[4], br[4];
#pragma unroll
    for (int ii = 0; ii < 4; ii++)
      ar[ii] = *reinterpret_cast<const bf16x8*>(rbA + buf * 16384 + ii * 1024);
#pragma unroll
    for (int j = 0; j < 4; j++)
      br[j] = *reinterpret_cast<const bf16x8*>(rbB + buf * 16384 + j * 1024);
    asm volatile("s_waitcnt vmcnt(2)" ::: "memory");  // Af(t+1) regs landed
    writeA(buf ^ 1);
    loadA(junk);
    asm volatile("s_waitcnt lgkmcnt(0)" ::: "memory");
    __builtin_amdgcn_sched_barrier(0);
    __builtin_amdgcn_s_setprio(1);
#pragma unroll
    for (int ii = 0; ii < 4; ii++)
#pragma unroll
      for (int j = 0; j < 4; j++)
        acc[ii][j] = mfma32(ar[ii], br[j], acc[ii][j]);
    __builtin_amdgcn_s_setprio(0);
    __builtin_amdgcn_s_barrier();                     // close phase 0
#pragma unroll
    for (int ii = 0; ii < 4; ii++)
      ar[ii] = *reinterpret_cast<const bf16x8*>(rbA + buf * 16384 + 4096 + ii * 1024);
    stB(buf);
    asm volatile("s_waitcnt lgkmcnt(0)" ::: "memory");
    __builtin_amdgcn_sched_barrier(0);
    __builtin_amdgcn_s_setprio(1);
#pragma unroll
    for (int ii = 0; ii < 4; ii++)
#pragma unroll
      for (int j = 0; j < 4; j++)
        acc[4 + ii][j] = mfma32(ar[ii], br[j], acc[4 + ii][j]);
    __builtin_amdgcn_s_setprio(0);
    asm volatile("s_waitcnt vmcnt(6)" ::: "memory");  // B(t+1) landed
    __builtin_amdgcn_s_barrier();                     // close phase 1
  };

#pragma unroll 1
  for (int it = 0; it < 16; ++it) {  // 32 K-tiles of 32
    group(0, it == 15);
    group(1, it == 15);
  }
  asm volatile("s_waitcnt vmcnt(0)" ::: "memory");

  const float scale = which == 0 ? 0.125f * LOG2E : 1.0f;
#pragma unroll
  for (int i = 0; i < 8; i++) {
#pragma unroll
    for (int j = 0; j < 4; j++) {
      const int colg = n0 + wc * 64 + j * 16 + rr;
      const float bvv = bq_[colg];
      if (which == 2) {  // V^T layout [B,H,DK,S]
        const int rowbase = m0 + wr * 128 + i * 16 + g * 4;
        const int bb = rowbase >> 11, s = rowbase & 2047;
        const int hh = colg >> 6, d = colg & 63;
        uint2 val;
        val.x = (unsigned int)f2bf(acc[i][j][0] + bvv) | ((unsigned int)f2bf(acc[i][j][1] + bvv) << 16);
        val.y = (unsigned int)f2bf(acc[i][j][2] + bvv) | ((unsigned int)f2bf(acc[i][j][3] + bvv) << 16);
        *reinterpret_cast<uint2*>(Qb + 2 * NE + ((long)((bb * CH + hh) * CD + d)) * CS + s) = val;
      } else {
        unsigned short* outp = Qb + (long)which * NE;
#pragma unroll
        for (int r = 0; r < 4; r++) {
          const int row = m0 + wr * 128 + i * 16 + g * 4 + r;
          outp[(long)row * CE + colg] = f2bf((acc[i][j][r] + bvv) * scale);
        }
      }
    }
  }
}

// ---------------- WO GEMM: 128x64 tile, 512 blocks (2/CU) ----------------
__global__ __launch_bounds__(256) void gemm_wo(const unsigned short* __restrict__ A,
                                               const unsigned short* __restrict__ W,
                                               const float* __restrict__ bias,
                                               float* __restrict__ out) {
  __shared__ __align__(16) unsigned short As[128 * 64];
  __shared__ __align__(16) unsigned short Bs[64 * 64];
  const int tid = threadIdx.x;
  const int lane = tid & 63, wave = tid >> 6;
  const int wm = (wave >> 1) * 64, wn = (wave & 1) * 32;
  const int g = lane >> 4, rr = lane & 15;
  const int m0 = blockIdx.x * 128, n0 = blockIdx.y * 64;
  const int K = CE;
  f32x4 acc[4][2] = {};

  for (int k0 = 0; k0 < K; k0 += 64) {
#pragma unroll
    for (int t = 0; t < 4; t++) {
      const int u = t * 256 + tid;
      const int row = u >> 3, ce = (u & 7) * 8;
      stage16(A + (long)(m0 + row) * K + k0 + ce, (char*)As + (t * 256 + (tid & 192)) * 16);
    }
#pragma unroll
    for (int t = 0; t < 2; t++) {
      const int u = t * 256 + tid;
      const int row = u >> 3, ce = (u & 7) * 8;
      stage16(W + (long)(n0 + row) * K + k0 + ce, (char*)Bs + (t * 256 + (tid & 192)) * 16);
    }
    __syncthreads();
#pragma unroll
    for (int kk = 0; kk < 2; kk++) {
      bf16x8 af[4], bfr[2];
#pragma unroll
      for (int i = 0; i < 4; i++)
        af[i] = *reinterpret_cast<const bf16x8*>(&As[(wm + i * 16 + rr) * 64 + kk * 32 + g * 8]);
#pragma unroll
      for (int j = 0; j < 2; j++)
        bfr[j] = *reinterpret_cast<const bf16x8*>(&Bs[(wn + j * 16 + rr) * 64 + kk * 32 + g * 8]);
#pragma unroll
      for (int i = 0; i < 4; i++)
#pragma unroll
        for (int j = 0; j < 2; j++)
          acc[i][j] = mfma32(af[i], bfr[j], acc[i][j]);
    }
    __syncthreads();
  }

#pragma unroll
  for (int i = 0; i < 4; i++)
#pragma unroll
    for (int j = 0; j < 2; j++) {
      const int colg = n0 + wn + j * 16 + rr;
      const float bvv = bias[colg];
#pragma unroll
      for (int r = 0; r < 4; r++) {
        const int row = m0 + wm + i * 16 + g * 4 + r;
        out[(long)row * CE + colg] = acc[i][j][r] + bvv;
      }
    }
}

// ---------------- Flash attention: BK=128, static softmax, mb16 precomputed ----------------
__global__ __launch_bounds__(256, 2) void attn_kernel(const unsigned short* __restrict__ Qb,
                                                      const unsigned short* __restrict__ Kb,
                                                      const unsigned short* __restrict__ Vtw,
                                                      const unsigned short* __restrict__ mb16,
                                                      const int* __restrict__ mask,
                                                      unsigned short* __restrict__ AO) {
  __shared__ __align__(16) unsigned char lds[65536];
  const int h = blockIdx.x, qt = blockIdx.y, b = blockIdx.z;
  const int tid = threadIdx.x;
  const int lane = tid & 63, w = tid >> 6;
  const int g = lane >> 4, c = lane & 15;
  const int qbase = qt * 128 + w * 32;

  bf16x8 qf[2][2];
#pragma unroll
  for (int qb = 0; qb < 2; qb++) {
    const unsigned short* Qrow = Qb + ((long)b * CS + qbase + qb * 16 + c) * CE + h * CD;
    qf[qb][0] = *reinterpret_cast<const bf16x8*>(Qrow + g * 8);
    qf[qb][1] = *reinterpret_cast<const bf16x8*>(Qrow + 32 + g * 8);
    if (mask[b * CS + qbase + qb * 16 + c] == 0) {
      qf[qb][0] = bf16x8{}; qf[qb][1] = bf16x8{};
    }
  }

  const unsigned char *kg[4], *vg[4];
  {
    const unsigned char* Ksrc = (const unsigned char*)(Kb + (long)b * CS * CE + h * CD);
    const unsigned char* Vsrc = (const unsigned char*)(Vtw + (long)(b * CH + h) * CD * CS);
    const int rr8 = lane >> 3;
    const int csw = ((lane & 7) << 4) ^ (rr8 << 4);
#pragma unroll
    for (int t = 0; t < 4; t++) {
      const int krow = t * 32 + w * 8 + rr8;
      const int key = (krow & 96) + ((krow >> 2) & 3) * 8 + ((krow >> 4) & 1) * 4 + (krow & 3);
      kg[t] = Ksrc + (long)key * (CE * 2) + csw;
      const int vrow = (t & 1) * 32 + w * 8 + rr8;
      vg[t] = Vsrc + (long)vrow * (CS * 2) + (t >> 1) * 128 + csw;
    }
  }
  const int sw = (c & 7) << 4;
  const unsigned char* rb0 = lds + c * 128 + ((g * 16) ^ sw);
  const unsigned char* rb1 = lds + c * 128 + ((64 + g * 16) ^ sw);

  const unsigned short* mbp0 = mb16 + ((long)b * CS + qbase + c) * CS + g * 8;
  const unsigned short* mbp1 = mb16 + ((long)b * CS + qbase + 16 + c) * CS + g * 8;

  f32x4 o[2][4] = {};
  f32x4 lsum4[2] = {};
  uint4 mbr[2][4];

  auto stage = [&](int bo) {
    unsigned char* kbuf = lds + bo;
    unsigned char* vbuf = lds + bo + 16384;
#pragma unroll
    for (int t = 0; t < 4; t++) {
      stage16(kg[t], kbuf + t * 4096 + w * 1024);
      stage16(vg[t], vbuf + (t >> 1) * 8192 + (t & 1) * 4096 + w * 1024);
      kg[t] += 128 * CE * 2;
      vg[t] += 128 * 2;
    }
  };
  auto load_mb = [&](bool adv) {
#pragma unroll
    for (int kb = 0; kb < 4; kb++) {
      mbr[0][kb] = *reinterpret_cast<const uint4*>(mbp0 + kb * 32);
      mbr[1][kb] = *reinterpret_cast<const uint4*>(mbp1 + kb * 32);
    }
    if (adv) { mbp0 += 128; mbp1 += 128; }
  };

  auto compute = [&](int bo, bool adv) {
    f32x4 sf[2][8];
    __builtin_amdgcn_s_setprio(1);
#pragma unroll
    for (int cb = 0; cb < 8; cb++) {
      const bf16x8 kf0 = *reinterpret_cast<const bf16x8*>(rb0 + bo + cb * 2048);
      const bf16x8 kf1 = *reinterpret_cast<const bf16x8*>(rb1 + bo + cb * 2048);
#pragma unroll
      for (int qb = 0; qb < 2; qb++) {
        const uint4 m = mbr[qb][cb >> 1];
        const f32x4 ci = (cb & 1) ? unpk(m.z, m.w) : unpk(m.x, m.y);
        f32x4 t = mfma32(kf0, qf[qb][0], ci);
        sf[qb][cb] = mfma32(kf1, qf[qb][1], t);
      }
    }
    __builtin_amdgcn_s_setprio(0);
    load_mb(adv);
    uint4 pw[2][4];
#pragma unroll
    for (int qb = 0; qb < 2; qb++)
#pragma unroll
      for (int kb = 0; kb < 4; kb++)
#pragma unroll
        for (int half = 0; half < 2; half++) {
          const int cb = 2 * kb + half;
          f32x4 pv;
          pv[0] = exp2r(sf[qb][cb][0]);
          pv[1] = exp2r(sf[qb][cb][1]);
          pv[2] = exp2r(sf[qb][cb][2]);
          pv[3] = exp2r(sf[qb][cb][3]);
          lsum4[qb] = lsum4[qb] + pv;
          if (half == 0) { pw[qb][kb].x = cvtpk(pv[0], pv[1]); pw[qb][kb].y = cvtpk(pv[2], pv[3]); }
          else           { pw[qb][kb].z = cvtpk(pv[0], pv[1]); pw[qb][kb].w = cvtpk(pv[2], pv[3]); }
        }
    __builtin_amdgcn_s_setprio(1);
#pragma unroll
    for (int nb = 0; nb < 4; nb++) {
#pragma unroll
      for (int kb = 0; kb < 4; kb++) {
        const unsigned char* rbx = (kb & 1) ? rb1 : rb0;
        const bf16x8 vf = *reinterpret_cast<const bf16x8*>(
            rbx + bo + 16384 + (kb >> 1) * 8192 + nb * 2048);
#pragma unroll
        for (int qb = 0; qb < 2; qb++)
          o[qb][nb] = mfma32(vf, __builtin_bit_cast(bf16x8, pw[qb][kb]), o[qb][nb]);
      }
    }
    __builtin_amdgcn_s_setprio(0);
  };

  stage(0);
  load_mb(true);
  stage(32768);

#pragma unroll 1
  for (int it = 0; it < 8; ++it) {
    asm volatile("s_waitcnt vmcnt(16)" ::: "memory");
    __builtin_amdgcn_s_barrier();
    __builtin_amdgcn_sched_barrier(0);
    compute(0, it < 7);
    __builtin_amdgcn_sched_barrier(0);
    __builtin_amdgcn_s_barrier();
    stage(0);
    asm volatile("s_waitcnt vmcnt(16)" ::: "memory");
    __builtin_amdgcn_s_barrier();
    __builtin_amdgcn_sched_barrier(0);
    compute(32768, it < 7);
    __builtin_amdgcn_sched_barrier(0);
    __builtin_amdgcn_s_barrier();
    stage(32768);
  }

#pragma unroll
  for (int qb = 0; qb < 2; qb++) {
    float lsum = (lsum4[qb][0] + lsum4[qb][1]) + (lsum4[qb][2] + lsum4[qb][3]);
    lsum += __shfl_xor(lsum, 16, 64);
    lsum += __shfl_xor(lsum, 32, 64);
    const float linv = 1.0f / lsum;
    unsigned short* Orow = AO + ((long)b * CS + qbase + qb * 16 + c) * CE + h * CD;
#pragma unroll
    for (int nb = 0; nb < 4; nb++) {
      uint2 val;
      val.x = (unsigned int)f2bf(o[qb][nb][0] * linv) | ((unsigned int)f2bf(o[qb][nb][1] * linv) << 16);
      val.y = (unsigned int)f2bf(o[qb][nb][2] * linv) | ((unsigned int)f2bf(o[qb][nb][3] * linv) << 16);
      *reinterpret_cast<uint2*>(Orow + nb * 16 + g * 4) = val;
    }
  }
  asm volatile("s_waitcnt vmcnt(0)" ::: "memory");
}

// ---------------- host ----------------
extern "C" void kernel_launch(void* const* d_in, const int* in_sizes, int n_in,
                              void* d_out, int out_size, void* d_ws, size_t ws_size,
                              hipStream_t stream) {
  (void)in_sizes; (void)n_in; (void)out_size; (void)ws_size;
  const float* x    = (const float*)d_in[0];
  const float* kv   = (const float*)d_in[1];
  const int*   mask = (const int*)d_in[2];
  const float* ab   = (const float*)d_in[3];
  const float* WQw  = (const float*)d_in[4];
  const float* WQb  = (const float*)d_in[5];
  const float* WKw  = (const float*)d_in[6];
  const float* WKb  = (const float*)d_in[7];
  const float* WVw  = (const float*)d_in[8];
  const float* WVb  = (const float*)d_in[9];
  const float* WOw  = (const float*)d_in[10];
  const float* WOb  = (const float*)d_in[11];
  float* out = (float*)d_out;

  const long NE = (long)CB * CS * CE;  // 4,194,304
  const long WE = (long)CE * CE;       // 1,048,576
  unsigned short* ws  = (unsigned short*)d_ws;
  unsigned short* wqb = ws;            // WQ|WK|WV contiguous = Wall
  unsigned short* wob = wqb + 3 * WE;
  unsigned short* Qb  = wob + WE;      // Q | K | Vt | AO contiguous
  unsigned short* AO  = Qb + 3 * NE;
  unsigned short* mb16 = AO + NE;      // CB*CS*CS bf16; total ws use = 58.7 MB

  wcvt_all<<<(int)((4 * WE) / 2048), 256, 0, stream>>>(WQw, WKw, WVw, WOw, wqb);

  // GEMM (192 blocks) + mbias (256 fat blocks, 8 strided iters each)
  gemm_qkv<<<dim3(192 + 256), 512, 0, stream>>>(x, kv, wqb, WQb, WKb, WVb, Qb,
                                                ab, mask, mb16);

  attn_kernel<<<dim3(CH, CS / 128, CB), 256, 0, stream>>>(
      Qb, Qb + NE, Qb + 2 * NE, mb16, mask, AO);

  gemm_wo<<<dim3(32, 16), 256, 0, stream>>>(AO, wob, WOb, out);
}

// Round 24
// 118.765 us; speedup vs baseline: 1.6160x; 1.0824x over previous
//
#include <hip/hip_runtime.h>

#define DEV static __device__ __forceinline__

typedef __attribute__((ext_vector_type(8))) __bf16 bf16x8;
typedef __attribute__((ext_vector_type(4))) float f32x4;

constexpr int CB = 2;     // batch
constexpr int CS = 2048;  // seq
constexpr int CE = 1024;  // embed
constexpr int CH = 16;    // heads
constexpr int CD = 64;    // head dim
constexpr float LOG2E = 1.44269504f;

DEV unsigned short f2bf(float x) {  // RNE f32 -> bf16 bits
  unsigned int u = __float_as_uint(x);
  u += 0x7fffu + ((u >> 16) & 1u);
  return (unsigned short)(u >> 16);
}

DEV f32x4 mfma32(bf16x8 a, bf16x8 b, f32x4 c) {  // 16x16x32
  return __builtin_amdgcn_mfma_f32_16x16x32_bf16(a, b, c, 0, 0, 0);
}

DEV unsigned int cvtpk(float lo, float hi) {  // pack 2 f32 -> 2 bf16 (RNE)
  unsigned int r;
  asm("v_cvt_pk_bf16_f32 %0, %1, %2" : "=v"(r) : "v"(lo), "v"(hi));
  return r;
}

DEV float exp2r(float x) {  // raw v_exp_f32
#if __has_builtin(__builtin_amdgcn_exp2f)
  return __builtin_amdgcn_exp2f(x);
#else
  float r; asm("v_exp_f32 %0, %1" : "=v"(r) : "v"(x)); return r;
#endif
}

DEV f32x4 unpk(unsigned int a, unsigned int b) {  // 4 packed bf16 -> f32x4
  f32x4 r;
  r[0] = __uint_as_float(a << 16);
  r[1] = __uint_as_float(a & 0xffff0000u);
  r[2] = __uint_as_float(b << 16);
  r[3] = __uint_as_float(b & 0xffff0000u);
  return r;
}

DEV void stage16(const void* g, void* l) {  // async global(16B/lane) -> LDS
  __builtin_amdgcn_global_load_lds(
      (const __attribute__((address_space(1))) unsigned int*)g,
      (__attribute__((address_space(3))) unsigned int*)l, 16, 0, 0);
}

// mbias (bf16, log2 domain): mq==0 -> 0 ; mq&&mk==0 -> -1e9*log2e ; else bias*log2e
DEV void mbias_body512(long idx, const float* __restrict__ bias, const int* __restrict__ mask,
                       unsigned short* __restrict__ mb16) {
  const int b = (int)(idx >> 22);
  const int q = (int)((idx >> 11) & (CS - 1));
  const int k0 = (int)(idx & (CS - 1));
  const bool mq = mask[b * CS + q] != 0;
  const int4 mk0 = *reinterpret_cast<const int4*>(mask + b * CS + k0);
  const int4 mk1 = *reinterpret_cast<const int4*>(mask + b * CS + k0 + 4);
  const float4 b0 = *reinterpret_cast<const float4*>(bias + idx);
  const float4 b1 = *reinterpret_cast<const float4*>(bias + idx + 4);
  const float NEG = -1e9f * LOG2E;
  float v[8];
  if (mq) {
    v[0] = (mk0.x != 0) ? b0.x * LOG2E : NEG;
    v[1] = (mk0.y != 0) ? b0.y * LOG2E : NEG;
    v[2] = (mk0.z != 0) ? b0.z * LOG2E : NEG;
    v[3] = (mk0.w != 0) ? b0.w * LOG2E : NEG;
    v[4] = (mk1.x != 0) ? b1.x * LOG2E : NEG;
    v[5] = (mk1.y != 0) ? b1.y * LOG2E : NEG;
    v[6] = (mk1.z != 0) ? b1.z * LOG2E : NEG;
    v[7] = (mk1.w != 0) ? b1.w * LOG2E : NEG;
  } else {
#pragma unroll
    for (int j = 0; j < 8; j++) v[j] = 0.f;  // uniform row (qf also zeroed in attn)
  }
  uint4 o;
  o.x = cvtpk(v[0], v[1]); o.y = cvtpk(v[2], v[3]);
  o.z = cvtpk(v[4], v[5]); o.w = cvtpk(v[6], v[7]);
  *reinterpret_cast<uint4*>(mb16 + idx) = o;
}

DEV void wcvt1_body(long i, const float* __restrict__ src, unsigned short* __restrict__ out) {
  float4 a = *reinterpret_cast<const float4*>(src + i);
  float4 b = *reinterpret_cast<const float4*>(src + i + 4);
  uint4 v;
  v.x = cvtpk(a.x, a.y); v.y = cvtpk(a.z, a.w);
  v.z = cvtpk(b.x, b.y); v.w = cvtpk(b.z, b.w);
  *reinterpret_cast<uint4*>(out + i) = v;
}

// ---------------- QKV GEMM v9: all-f32 inputs (A and W), fused side work ----------------
// 1D grid: [0,192) GEMM tiles; [192,448) mbias fat blocks (8 strided iters);
// [448,480) WO f32->bf16 cvt (8 strided iters; WO not read here -> no race).
// GEMM: both A and B reg-staged f32 -> cvt_pk -> swizzled ds_write. Per tile:
//   P0: vmcnt(4) [A(t+1) landed] -> writeA, loadA(t+2); lgkm; 16 MFMA; barrier
//   P1: vmcnt(4) [B(t+1) landed] -> writeB, loadB(t+2); lgkm; 16 MFMA; barrier
// Steady queue at P0 head = [A(t+1):4][B(t+1):4]. Junk tail loads clamped in-bounds.
__global__ __launch_bounds__(512) void gemm_qkv(const float* __restrict__ xf,
                                                const float* __restrict__ kvf,
                                                const float* __restrict__ WQw,
                                                const float* __restrict__ WKw,
                                                const float* __restrict__ WVw,
                                                const float* __restrict__ bq,
                                                const float* __restrict__ bk,
                                                const float* __restrict__ bv,
                                                unsigned short* __restrict__ Qb,
                                                const float* __restrict__ bias,
                                                const int* __restrict__ mask,
                                                unsigned short* __restrict__ mb16,
                                                const float* __restrict__ WOw,
                                                unsigned short* __restrict__ wob) {
  __shared__ __align__(16) unsigned char ldsA[32768];  // 2 x 16KB
  __shared__ __align__(16) unsigned char ldsB[32768];
  const int bx = blockIdx.x;
  const int tid = threadIdx.x;
  if (bx >= 192) {
    if (bx < 448) {  // ---- mbias side-block: 8 grid-strided iterations ----
      const long base = ((long)(bx - 192) * 512 + tid) * 8;
      const long stride = 256L * 512 * 8;  // 1,048,576 elems per round
#pragma unroll
      for (int itr = 0; itr < 8; itr++)
        mbias_body512(base + (long)itr * stride, bias, mask, mb16);
    } else {         // ---- WO weight cvt side-block ----
      const long base = ((long)(bx - 448) * 512 + tid) * 8;
      const long stride = 32L * 512 * 8;   // 131,072 elems per round
#pragma unroll
      for (int itr = 0; itr < 8; itr++)
        wcvt1_body(base + (long)itr * stride, WOw, wob);
    }
    return;
  }
  const long NE = (long)CB * CS * CE;
  const int mx = bx & 15, ny = bx >> 4;
  const int which = ny >> 2;                  // 0=Q 1=K 2=V
  const int n0 = (ny & 3) * 256;
  const int m0 = mx * 256;
  const float* Ax = which == 0 ? xf : kvf;
  const float* Bw = which == 0 ? WQw : which == 1 ? WKw : WVw;
  const float* bq_ = which == 0 ? bq : which == 1 ? bk : bv;

  const int lane = tid & 63, w = tid >> 6;
  const int wr = w >> 2, wc = w & 3;
  const int g = lane >> 4, rr = lane & 15;

  const int srow = tid >> 2;                                    // 0..127
  const int ecol = ((tid & 3) * 8) ^ (((tid >> 5) & 1) * 16);   // swizzled elem col
  const float* afp0 = Ax + (long)(m0 + srow) * CE + ecol;
  const float* afp1 = Ax + (long)(m0 + 128 + srow) * CE + ecol;
  const float* afb0 = afp0;  // clamped junk sources (stay in-bounds)
  const float* afb1 = afp1;
  const float* bfp0 = Bw + (long)(n0 + srow) * CE + ecol;
  const float* bfp1 = Bw + (long)(n0 + 128 + srow) * CE + ecol;
  const float* bfb0 = bfp0;
  const float* bfb1 = bfp1;

  const int cswz = (g * 16) ^ (((rr >> 3) & 1) << 5);
  const unsigned char* rbA = ldsA + wr * 8192 + rr * 64 + cswz;
  const unsigned char* rbB = ldsB + wc * 4096 + rr * 64 + cswz;

  f32x4 acc[8][4] = {};
  float4 afr0, afr1, afr2, afr3;  // A f32 staging regs
  float4 bfr0, bfr1, bfr2, bfr3;  // B f32 staging regs

  auto loadA = [&](bool junk) {  // 4 vmem
    const float* p0 = junk ? afb0 : afp0;
    const float* p1 = junk ? afb1 : afp1;
    afr0 = *reinterpret_cast<const float4*>(p0);
    afr1 = *reinterpret_cast<const float4*>(p0 + 4);
    afr2 = *reinterpret_cast<const float4*>(p1);
    afr3 = *reinterpret_cast<const float4*>(p1 + 4);
    if (!junk) { afp0 += 32; afp1 += 32; }
  };
  auto loadB = [&](bool junk) {  // 4 vmem
    const float* p0 = junk ? bfb0 : bfp0;
    const float* p1 = junk ? bfb1 : bfp1;
    bfr0 = *reinterpret_cast<const float4*>(p0);
    bfr1 = *reinterpret_cast<const float4*>(p0 + 4);
    bfr2 = *reinterpret_cast<const float4*>(p1);
    bfr3 = *reinterpret_cast<const float4*>(p1 + 4);
    if (!junk) { bfp0 += 32; bfp1 += 32; }
  };
  auto writeA = [&](int buf) {  // cvt + 2x ds_write_b128
    uint4 w0v, w1v;
    w0v.x = cvtpk(afr0.x, afr0.y); w0v.y = cvtpk(afr0.z, afr0.w);
    w0v.z = cvtpk(afr1.x, afr1.y); w0v.w = cvtpk(afr1.z, afr1.w);
    w1v.x = cvtpk(afr2.x, afr2.y); w1v.y = cvtpk(afr2.z, afr2.w);
    w1v.z = cvtpk(afr3.x, afr3.y); w1v.w = cvtpk(afr3.z, afr3.w);
    *reinterpret_cast<uint4*>(ldsA + buf * 16384 + tid * 16) = w0v;
    *reinterpret_cast<uint4*>(ldsA + buf * 16384 + 8192 + tid * 16) = w1v;
  };
  auto writeB = [&](int buf) {  // cvt + 2x ds_write_b128
    uint4 w0v, w1v;
    w0v.x = cvtpk(bfr0.x, bfr0.y); w0v.y = cvtpk(bfr0.z, bfr0.w);
    w0v.z = cvtpk(bfr1.x, bfr1.y); w0v.w = cvtpk(bfr1.z, bfr1.w);
    w1v.x = cvtpk(bfr2.x, bfr2.y); w1v.y = cvtpk(bfr2.z, bfr2.w);
    w1v.z = cvtpk(bfr3.x, bfr3.y); w1v.w = cvtpk(bfr3.z, bfr3.w);
    *reinterpret_cast<uint4*>(ldsB + buf * 16384 + tid * 16) = w0v;
    *reinterpret_cast<uint4*>(ldsB + buf * 16384 + 8192 + tid * 16) = w1v;
  };

  // prologue -> establish entry invariant: outstanding = [A(1):4][B(1):4]
  loadA(false);                                     // A0 [4]
  loadB(false);                                     // B0 [4]
  asm volatile("s_waitcnt vmcnt(4)" ::: "memory");  // A0 landed
  writeA(0);
  loadA(false);                                     // A1 [4]
  asm volatile("s_waitcnt vmcnt(4)" ::: "memory");  // B0 landed
  writeB(0);
  loadB(false);                                     // B1 [4]
  asm volatile("s_waitcnt lgkmcnt(0)" ::: "memory");
  __builtin_amdgcn_s_barrier();

  auto group = [&](int buf, bool junk) {
    bf16x8 ar[4], br[4];
    // ---- phase 0: acc[0..3] x B ----
#pragma unroll
    for (int ii = 0; ii < 4; ii++)
      ar[ii] = *reinterpret_cast<const bf16x8*>(rbA + buf * 16384 + ii * 1024);
#pragma unroll
    for (int j = 0; j < 4; j++)
      br[j] = *reinterpret_cast<const bf16x8*>(rbB + buf * 16384 + j * 1024);
    asm volatile("s_waitcnt vmcnt(4)" ::: "memory");  // A(t+1) regs landed
    writeA(buf ^ 1);
    loadA(junk);                                      // A(t+2) [4]
    asm volatile("s_waitcnt lgkmcnt(0)" ::: "memory");
    __builtin_amdgcn_sched_barrier(0);
    __builtin_amdgcn_s_setprio(1);
#pragma unroll
    for (int ii = 0; ii < 4; ii++)
#pragma unroll
      for (int j = 0; j < 4; j++)
        acc[ii][j] = mfma32(ar[ii], br[j], acc[ii][j]);
    __builtin_amdgcn_s_setprio(0);
    __builtin_amdgcn_s_barrier();                     // close phase 0
    // ---- phase 1: acc[4..7] x B ----
#pragma unroll
    for (int ii = 0; ii < 4; ii++)
      ar[ii] = *reinterpret_cast<const bf16x8*>(rbA + buf * 16384 + 4096 + ii * 1024);
    asm volatile("s_waitcnt vmcnt(4)" ::: "memory");  // B(t+1) regs landed
    writeB(buf ^ 1);
    loadB(junk);                                      // B(t+2) [4]
    asm volatile("s_waitcnt lgkmcnt(0)" ::: "memory");
    __builtin_amdgcn_sched_barrier(0);
    __builtin_amdgcn_s_setprio(1);
#pragma unroll
    for (int ii = 0; ii < 4; ii++)
#pragma unroll
      for (int j = 0; j < 4; j++)
        acc[4 + ii][j] = mfma32(ar[ii], br[j], acc[4 + ii][j]);
    __builtin_amdgcn_s_setprio(0);
    __builtin_amdgcn_s_barrier();                     // close phase 1
  };

#pragma unroll 1
  for (int it = 0; it < 16; ++it) {  // 32 K-tiles of 32
    group(0, it == 15);
    group(1, it == 15);
  }
  asm volatile("s_waitcnt vmcnt(0)" ::: "memory");  // drain junk loads

  const float scale = which == 0 ? 0.125f * LOG2E : 1.0f;
#pragma unroll
  for (int i = 0; i < 8; i++) {
#pragma unroll
    for (int j = 0; j < 4; j++) {
      const int colg = n0 + wc * 64 + j * 16 + rr;
      const float bvv = bq_[colg];
      if (which == 2) {  // V^T layout [B,H,DK,S]
        const int rowbase = m0 + wr * 128 + i * 16 + g * 4;
        const int bb = rowbase >> 11, s = rowbase & 2047;
        const int hh = colg >> 6, d = colg & 63;
        uint2 val;
        val.x = (unsigned int)f2bf(acc[i][j][0] + bvv) | ((unsigned int)f2bf(acc[i][j][1] + bvv) << 16);
        val.y = (unsigned int)f2bf(acc[i][j][2] + bvv) | ((unsigned int)f2bf(acc[i][j][3] + bvv) << 16);
        *reinterpret_cast<uint2*>(Qb + 2 * NE + ((long)((bb * CH + hh) * CD + d)) * CS + s) = val;
      } else {
        unsigned short* outp = Qb + (long)which * NE;
#pragma unroll
        for (int r = 0; r < 4; r++) {
          const int row = m0 + wr * 128 + i * 16 + g * 4 + r;
          outp[(long)row * CE + colg] = f2bf((acc[i][j][r] + bvv) * scale);
        }
      }
    }
  }
}

// ---------------- WO GEMM: 128x64 tile, 512 blocks (2/CU) ----------------
__global__ __launch_bounds__(256) void gemm_wo(const unsigned short* __restrict__ A,
                                               const unsigned short* __restrict__ W,
                                               const float* __restrict__ bias,
                                               float* __restrict__ out) {
  __shared__ __align__(16) unsigned short As[128 * 64];
  __shared__ __align__(16) unsigned short Bs[64 * 64];
  const int tid = threadIdx.x;
  const int lane = tid & 63, wave = tid >> 6;
  const int wm = (wave >> 1) * 64, wn = (wave & 1) * 32;
  const int g = lane >> 4, rr = lane & 15;
  const int m0 = blockIdx.x * 128, n0 = blockIdx.y * 64;
  const int K = CE;
  f32x4 acc[4][2] = {};

  for (int k0 = 0; k0 < K; k0 += 64) {
#pragma unroll
    for (int t = 0; t < 4; t++) {
      const int u = t * 256 + tid;
      const int row = u >> 3, ce = (u & 7) * 8;
      stage16(A + (long)(m0 + row) * K + k0 + ce, (char*)As + (t * 256 + (tid & 192)) * 16);
    }
#pragma unroll
    for (int t = 0; t < 2; t++) {
      const int u = t * 256 + tid;
      const int row = u >> 3, ce = (u & 7) * 8;
      stage16(W + (long)(n0 + row) * K + k0 + ce, (char*)Bs + (t * 256 + (tid & 192)) * 16);
    }
    __syncthreads();
#pragma unroll
    for (int kk = 0; kk < 2; kk++) {
      bf16x8 af[4], bfr[2];
#pragma unroll
      for (int i = 0; i < 4; i++)
        af[i] = *reinterpret_cast<const bf16x8*>(&As[(wm + i * 16 + rr) * 64 + kk * 32 + g * 8]);
#pragma unroll
      for (int j = 0; j < 2; j++)
        bfr[j] = *reinterpret_cast<const bf16x8*>(&Bs[(wn + j * 16 + rr) * 64 + kk * 32 + g * 8]);
#pragma unroll
      for (int i = 0; i < 4; i++)
#pragma unroll
        for (int j = 0; j < 2; j++)
          acc[i][j] = mfma32(af[i], bfr[j], acc[i][j]);
    }
    __syncthreads();
  }

#pragma unroll
  for (int i = 0; i < 4; i++)
#pragma unroll
    for (int j = 0; j < 2; j++) {
      const int colg = n0 + wn + j * 16 + rr;
      const float bvv = bias[colg];
#pragma unroll
      for (int r = 0; r < 4; r++) {
        const int row = m0 + wm + i * 16 + g * 4 + r;
        out[(long)row * CE + colg] = acc[i][j][r] + bvv;
      }
    }
}

// ---------------- Flash attention: BK=128, static softmax, mb16 precomputed ----------------
__global__ __launch_bounds__(256, 2) void attn_kernel(const unsigned short* __restrict__ Qb,
                                                      const unsigned short* __restrict__ Kb,
                                                      const unsigned short* __restrict__ Vtw,
                                                      const unsigned short* __restrict__ mb16,
                                                      const int* __restrict__ mask,
                                                      unsigned short* __restrict__ AO) {
  __shared__ __align__(16) unsigned char lds[65536];
  const int h = blockIdx.x, qt = blockIdx.y, b = blockIdx.z;
  const int tid = threadIdx.x;
  const int lane = tid & 63, w = tid >> 6;
  const int g = lane >> 4, c = lane & 15;
  const int qbase = qt * 128 + w * 32;

  bf16x8 qf[2][2];
#pragma unroll
  for (int qb = 0; qb < 2; qb++) {
    const unsigned short* Qrow = Qb + ((long)b * CS + qbase + qb * 16 + c) * CE + h * CD;
    qf[qb][0] = *reinterpret_cast<const bf16x8*>(Qrow + g * 8);
    qf[qb][1] = *reinterpret_cast<const bf16x8*>(Qrow + 32 + g * 8);
    if (mask[b * CS + qbase + qb * 16 + c] == 0) {
      qf[qb][0] = bf16x8{}; qf[qb][1] = bf16x8{};
    }
  }

  const unsigned char *kg[4], *vg[4];
  {
    const unsigned char* Ksrc = (const unsigned char*)(Kb + (long)b * CS * CE + h * CD);
    const unsigned char* Vsrc = (const unsigned char*)(Vtw + (long)(b * CH + h) * CD * CS);
    const int rr8 = lane >> 3;
    const int csw = ((lane & 7) << 4) ^ (rr8 << 4);
#pragma unroll
    for (int t = 0; t < 4; t++) {
      const int krow = t * 32 + w * 8 + rr8;
      const int key = (krow & 96) + ((krow >> 2) & 3) * 8 + ((krow >> 4) & 1) * 4 + (krow & 3);
      kg[t] = Ksrc + (long)key * (CE * 2) + csw;
      const int vrow = (t & 1) * 32 + w * 8 + rr8;
      vg[t] = Vsrc + (long)vrow * (CS * 2) + (t >> 1) * 128 + csw;
    }
  }
  const int sw = (c & 7) << 4;
  const unsigned char* rb0 = lds + c * 128 + ((g * 16) ^ sw);
  const unsigned char* rb1 = lds + c * 128 + ((64 + g * 16) ^ sw);

  const unsigned short* mbp0 = mb16 + ((long)b * CS + qbase + c) * CS + g * 8;
  const unsigned short* mbp1 = mb16 + ((long)b * CS + qbase + 16 + c) * CS + g * 8;

  f32x4 o[2][4] = {};
  f32x4 lsum4[2] = {};
  uint4 mbr[2][4];

  auto stage = [&](int bo) {
    unsigned char* kbuf = lds + bo;
    unsigned char* vbuf = lds + bo + 16384;
#pragma unroll
    for (int t = 0; t < 4; t++) {
      stage16(kg[t], kbuf + t * 4096 + w * 1024);
      stage16(vg[t], vbuf + (t >> 1) * 8192 + (t & 1) * 4096 + w * 1024);
      kg[t] += 128 * CE * 2;
      vg[t] += 128 * 2;
    }
  };
  auto load_mb = [&](bool adv) {
#pragma unroll
    for (int kb = 0; kb < 4; kb++) {
      mbr[0][kb] = *reinterpret_cast<const uint4*>(mbp0 + kb * 32);
      mbr[1][kb] = *reinterpret_cast<const uint4*>(mbp1 + kb * 32);
    }
    if (adv) { mbp0 += 128; mbp1 += 128; }
  };

  auto compute = [&](int bo, bool adv) {
    f32x4 sf[2][8];
    __builtin_amdgcn_s_setprio(1);
#pragma unroll
    for (int cb = 0; cb < 8; cb++) {
      const bf16x8 kf0 = *reinterpret_cast<const bf16x8*>(rb0 + bo + cb * 2048);
      const bf16x8 kf1 = *reinterpret_cast<const bf16x8*>(rb1 + bo + cb * 2048);
#pragma unroll
      for (int qb = 0; qb < 2; qb++) {
        const uint4 m = mbr[qb][cb >> 1];
        const f32x4 ci = (cb & 1) ? unpk(m.z, m.w) : unpk(m.x, m.y);
        f32x4 t = mfma32(kf0, qf[qb][0], ci);
        sf[qb][cb] = mfma32(kf1, qf[qb][1], t);
      }
    }
    __builtin_amdgcn_s_setprio(0);
    load_mb(adv);
    uint4 pw[2][4];
#pragma unroll
    for (int qb = 0; qb < 2; qb++)
#pragma unroll
      for (int kb = 0; kb < 4; kb++)
#pragma unroll
        for (int half = 0; half < 2; half++) {
          const int cb = 2 * kb + half;
          f32x4 pv;
          pv[0] = exp2r(sf[qb][cb][0]);
          pv[1] = exp2r(sf[qb][cb][1]);
          pv[2] = exp2r(sf[qb][cb][2]);
          pv[3] = exp2r(sf[qb][cb][3]);
          lsum4[qb] = lsum4[qb] + pv;
          if (half == 0) { pw[qb][kb].x = cvtpk(pv[0], pv[1]); pw[qb][kb].y = cvtpk(pv[2], pv[3]); }
          else           { pw[qb][kb].z = cvtpk(pv[0], pv[1]); pw[qb][kb].w = cvtpk(pv[2], pv[3]); }
        }
    __builtin_amdgcn_s_setprio(1);
#pragma unroll
    for (int nb = 0; nb < 4; nb++) {
#pragma unroll
      for (int kb = 0; kb < 4; kb++) {
        const unsigned char* rbx = (kb & 1) ? rb1 : rb0;
        const bf16x8 vf = *reinterpret_cast<const bf16x8*>(
            rbx + bo + 16384 + (kb >> 1) * 8192 + nb * 2048);
#pragma unroll
        for (int qb = 0; qb < 2; qb++)
          o[qb][nb] = mfma32(vf, __builtin_bit_cast(bf16x8, pw[qb][kb]), o[qb][nb]);
      }
    }
    __builtin_amdgcn_s_setprio(0);
  };

  stage(0);
  load_mb(true);
  stage(32768);

#pragma unroll 1
  for (int it = 0; it < 8; ++it) {
    asm volatile("s_waitcnt vmcnt(16)" ::: "memory");
    __builtin_amdgcn_s_barrier();
    __builtin_amdgcn_sched_barrier(0);
    compute(0, it < 7);
    __builtin_amdgcn_sched_barrier(0);
    __builtin_amdgcn_s_barrier();
    stage(0);
    asm volatile("s_waitcnt vmcnt(16)" ::: "memory");
    __builtin_amdgcn_s_barrier();
    __builtin_amdgcn_sched_barrier(0);
    compute(32768, it < 7);
    __builtin_amdgcn_sched_barrier(0);
    __builtin_amdgcn_s_barrier();
    stage(32768);
  }

#pragma unroll
  for (int qb = 0; qb < 2; qb++) {
    float lsum = (lsum4[qb][0] + lsum4[qb][1]) + (lsum4[qb][2] + lsum4[qb][3]);
    lsum += __shfl_xor(lsum, 16, 64);
    lsum += __shfl_xor(lsum, 32, 64);
    const float linv = 1.0f / lsum;
    unsigned short* Orow = AO + ((long)b * CS + qbase + qb * 16 + c) * CE + h * CD;
#pragma unroll
    for (int nb = 0; nb < 4; nb++) {
      uint2 val;
      val.x = (unsigned int)f2bf(o[qb][nb][0] * linv) | ((unsigned int)f2bf(o[qb][nb][1] * linv) << 16);
      val.y = (unsigned int)f2bf(o[qb][nb][2] * linv) | ((unsigned int)f2bf(o[qb][nb][3] * linv) << 16);
      *reinterpret_cast<uint2*>(Orow + nb * 16 + g * 4) = val;
    }
  }
  asm volatile("s_waitcnt vmcnt(0)" ::: "memory");
}

// ---------------- host ----------------
extern "C" void kernel_launch(void* const* d_in, const int* in_sizes, int n_in,
                              void* d_out, int out_size, void* d_ws, size_t ws_size,
                              hipStream_t stream) {
  (void)in_sizes; (void)n_in; (void)out_size; (void)ws_size;
  const float* x    = (const float*)d_in[0];
  const float* kv   = (const float*)d_in[1];
  const int*   mask = (const int*)d_in[2];
  const float* ab   = (const float*)d_in[3];
  const float* WQw  = (const float*)d_in[4];
  const float* WQb  = (const float*)d_in[5];
  const float* WKw  = (const float*)d_in[6];
  const float* WKb  = (const float*)d_in[7];
  const float* WVw  = (const float*)d_in[8];
  const float* WVb  = (const float*)d_in[9];
  const float* WOw  = (const float*)d_in[10];
  const float* WOb  = (const float*)d_in[11];
  float* out = (float*)d_out;

  const long NE = (long)CB * CS * CE;  // 4,194,304
  const long WE = (long)CE * CE;       // 1,048,576
  unsigned short* ws  = (unsigned short*)d_ws;
  unsigned short* wob = ws + 3 * WE;   // WO bf16 (written by qkv side-blocks)
  unsigned short* Qb  = wob + WE;      // Q | K | Vt | AO contiguous
  unsigned short* AO  = Qb + 3 * NE;
  unsigned short* mb16 = AO + NE;      // CB*CS*CS bf16; total ws use = 58.7 MB

  // single fused front kernel: QKV GEMM (f32 inputs) + mbias + WO-cvt side work
  gemm_qkv<<<dim3(192 + 256 + 32), 512, 0, stream>>>(
      x, kv, WQw, WKw, WVw, WQb, WKb, WVb, Qb, ab, mask, mb16, WOw, wob);

  attn_kernel<<<dim3(CH, CS / 128, CB), 256, 0, stream>>>(
      Qb, Qb + NE, Qb + 2 * NE, mb16, mask, AO);

  gemm_wo<<<dim3(32, 16), 256, 0, stream>>>(AO, wob, WOb, out);
}

// Round 25
// 115.688 us; speedup vs baseline: 1.6590x; 1.0266x over previous
//
#include <hip/hip_runtime.h>

#define DEV static __device__ __forceinline__

typedef __attribute__((ext_vector_type(8))) __bf16 bf16x8;
typedef __attribute__((ext_vector_type(4))) float f32x4;

constexpr int CB = 2;     // batch
constexpr int CS = 2048;  // seq
constexpr int CE = 1024;  // embed
constexpr int CH = 16;    // heads
constexpr int CD = 64;    // head dim
constexpr float LOG2E = 1.44269504f;

DEV unsigned short f2bf(float x) {  // RNE f32 -> bf16 bits
  unsigned int u = __float_as_uint(x);
  u += 0x7fffu + ((u >> 16) & 1u);
  return (unsigned short)(u >> 16);
}

DEV f32x4 mfma32(bf16x8 a, bf16x8 b, f32x4 c) {  // 16x16x32
  return __builtin_amdgcn_mfma_f32_16x16x32_bf16(a, b, c, 0, 0, 0);
}

DEV unsigned int cvtpk(float lo, float hi) {  // pack 2 f32 -> 2 bf16 (RNE)
  unsigned int r;
  asm("v_cvt_pk_bf16_f32 %0, %1, %2" : "=v"(r) : "v"(lo), "v"(hi));
  return r;
}

DEV float exp2r(float x) {  // raw v_exp_f32
#if __has_builtin(__builtin_amdgcn_exp2f)
  return __builtin_amdgcn_exp2f(x);
#else
  float r; asm("v_exp_f32 %0, %1" : "=v"(r) : "v"(x)); return r;
#endif
}

DEV f32x4 unpk(unsigned int a, unsigned int b) {  // 4 packed bf16 -> f32x4
  f32x4 r;
  r[0] = __uint_as_float(a << 16);
  r[1] = __uint_as_float(a & 0xffff0000u);
  r[2] = __uint_as_float(b << 16);
  r[3] = __uint_as_float(b & 0xffff0000u);
  return r;
}

DEV void stage16(const void* g, void* l) {  // async global(16B/lane) -> LDS
  __builtin_amdgcn_global_load_lds(
      (const __attribute__((address_space(1))) unsigned int*)g,
      (__attribute__((address_space(3))) unsigned int*)l, 16, 0, 0);
}

// mbias (bf16, log2 domain): mq==0 -> 0 ; mq&&mk==0 -> -1e9*log2e ; else bias*log2e
DEV void mbias_body512(long idx, const float* __restrict__ bias, const int* __restrict__ mask,
                       unsigned short* __restrict__ mb16) {
  const int b = (int)(idx >> 22);
  const int q = (int)((idx >> 11) & (CS - 1));
  const int k0 = (int)(idx & (CS - 1));
  const bool mq = mask[b * CS + q] != 0;
  const int4 mk0 = *reinterpret_cast<const int4*>(mask + b * CS + k0);
  const int4 mk1 = *reinterpret_cast<const int4*>(mask + b * CS + k0 + 4);
  const float4 b0 = *reinterpret_cast<const float4*>(bias + idx);
  const float4 b1 = *reinterpret_cast<const float4*>(bias + idx + 4);
  const float NEG = -1e9f * LOG2E;
  float v[8];
  if (mq) {
    v[0] = (mk0.x != 0) ? b0.x * LOG2E : NEG;
    v[1] = (mk0.y != 0) ? b0.y * LOG2E : NEG;
    v[2] = (mk0.z != 0) ? b0.z * LOG2E : NEG;
    v[3] = (mk0.w != 0) ? b0.w * LOG2E : NEG;
    v[4] = (mk1.x != 0) ? b1.x * LOG2E : NEG;
    v[5] = (mk1.y != 0) ? b1.y * LOG2E : NEG;
    v[6] = (mk1.z != 0) ? b1.z * LOG2E : NEG;
    v[7] = (mk1.w != 0) ? b1.w * LOG2E : NEG;
  } else {
#pragma unroll
    for (int j = 0; j < 8; j++) v[j] = 0.f;  // uniform row (qf also zeroed in attn)
  }
  uint4 o;
  o.x = cvtpk(v[0], v[1]); o.y = cvtpk(v[2], v[3]);
  o.z = cvtpk(v[4], v[5]); o.w = cvtpk(v[6], v[7]);
  *reinterpret_cast<uint4*>(mb16 + idx) = o;
}

DEV void wcvt1_body(long i, const float* __restrict__ src, unsigned short* __restrict__ out) {
  float4 a = *reinterpret_cast<const float4*>(src + i);
  float4 b = *reinterpret_cast<const float4*>(src + i + 4);
  uint4 v;
  v.x = cvtpk(a.x, a.y); v.y = cvtpk(a.z, a.w);
  v.z = cvtpk(b.x, b.y); v.w = cvtpk(b.z, b.w);
  *reinterpret_cast<uint4*>(out + i) = v;
}

// ---------------- QKV GEMM v9 (R24, unchanged): all-f32 inputs, fused side work ----------------
__global__ __launch_bounds__(512) void gemm_qkv(const float* __restrict__ xf,
                                                const float* __restrict__ kvf,
                                                const float* __restrict__ WQw,
                                                const float* __restrict__ WKw,
                                                const float* __restrict__ WVw,
                                                const float* __restrict__ bq,
                                                const float* __restrict__ bk,
                                                const float* __restrict__ bv,
                                                unsigned short* __restrict__ Qb,
                                                const float* __restrict__ bias,
                                                const int* __restrict__ mask,
                                                unsigned short* __restrict__ mb16,
                                                const float* __restrict__ WOw,
                                                unsigned short* __restrict__ wob) {
  __shared__ __align__(16) unsigned char ldsA[32768];  // 2 x 16KB
  __shared__ __align__(16) unsigned char ldsB[32768];
  const int bx = blockIdx.x;
  const int tid = threadIdx.x;
  if (bx >= 192) {
    if (bx < 448) {  // ---- mbias side-block: 8 grid-strided iterations ----
      const long base = ((long)(bx - 192) * 512 + tid) * 8;
      const long stride = 256L * 512 * 8;  // 1,048,576 elems per round
#pragma unroll
      for (int itr = 0; itr < 8; itr++)
        mbias_body512(base + (long)itr * stride, bias, mask, mb16);
    } else {         // ---- WO weight cvt side-block ----
      const long base = ((long)(bx - 448) * 512 + tid) * 8;
      const long stride = 32L * 512 * 8;   // 131,072 elems per round
#pragma unroll
      for (int itr = 0; itr < 8; itr++)
        wcvt1_body(base + (long)itr * stride, WOw, wob);
    }
    return;
  }
  const long NE = (long)CB * CS * CE;
  const int mx = bx & 15, ny = bx >> 4;
  const int which = ny >> 2;                  // 0=Q 1=K 2=V
  const int n0 = (ny & 3) * 256;
  const int m0 = mx * 256;
  const float* Ax = which == 0 ? xf : kvf;
  const float* Bw = which == 0 ? WQw : which == 1 ? WKw : WVw;
  const float* bq_ = which == 0 ? bq : which == 1 ? bk : bv;

  const int lane = tid & 63, w = tid >> 6;
  const int wr = w >> 2, wc = w & 3;
  const int g = lane >> 4, rr = lane & 15;

  const int srow = tid >> 2;                                    // 0..127
  const int ecol = ((tid & 3) * 8) ^ (((tid >> 5) & 1) * 16);   // swizzled elem col
  const float* afp0 = Ax + (long)(m0 + srow) * CE + ecol;
  const float* afp1 = Ax + (long)(m0 + 128 + srow) * CE + ecol;
  const float* afb0 = afp0;  // clamped junk sources (stay in-bounds)
  const float* afb1 = afp1;
  const float* bfp0 = Bw + (long)(n0 + srow) * CE + ecol;
  const float* bfp1 = Bw + (long)(n0 + 128 + srow) * CE + ecol;
  const float* bfb0 = bfp0;
  const float* bfb1 = bfp1;

  const int cswz = (g * 16) ^ (((rr >> 3) & 1) << 5);
  const unsigned char* rbA = ldsA + wr * 8192 + rr * 64 + cswz;
  const unsigned char* rbB = ldsB + wc * 4096 + rr * 64 + cswz;

  f32x4 acc[8][4] = {};
  float4 afr0, afr1, afr2, afr3;  // A f32 staging regs
  float4 bfr0, bfr1, bfr2, bfr3;  // B f32 staging regs

  auto loadA = [&](bool junk) {  // 4 vmem
    const float* p0 = junk ? afb0 : afp0;
    const float* p1 = junk ? afb1 : afp1;
    afr0 = *reinterpret_cast<const float4*>(p0);
    afr1 = *reinterpret_cast<const float4*>(p0 + 4);
    afr2 = *reinterpret_cast<const float4*>(p1);
    afr3 = *reinterpret_cast<const float4*>(p1 + 4);
    if (!junk) { afp0 += 32; afp1 += 32; }
  };
  auto loadB = [&](bool junk) {  // 4 vmem
    const float* p0 = junk ? bfb0 : bfp0;
    const float* p1 = junk ? bfb1 : bfp1;
    bfr0 = *reinterpret_cast<const float4*>(p0);
    bfr1 = *reinterpret_cast<const float4*>(p0 + 4);
    bfr2 = *reinterpret_cast<const float4*>(p1);
    bfr3 = *reinterpret_cast<const float4*>(p1 + 4);
    if (!junk) { bfp0 += 32; bfp1 += 32; }
  };
  auto writeA = [&](int buf) {  // cvt + 2x ds_write_b128
    uint4 w0v, w1v;
    w0v.x = cvtpk(afr0.x, afr0.y); w0v.y = cvtpk(afr0.z, afr0.w);
    w0v.z = cvtpk(afr1.x, afr1.y); w0v.w = cvtpk(afr1.z, afr1.w);
    w1v.x = cvtpk(afr2.x, afr2.y); w1v.y = cvtpk(afr2.z, afr2.w);
    w1v.z = cvtpk(afr3.x, afr3.y); w1v.w = cvtpk(afr3.z, afr3.w);
    *reinterpret_cast<uint4*>(ldsA + buf * 16384 + tid * 16) = w0v;
    *reinterpret_cast<uint4*>(ldsA + buf * 16384 + 8192 + tid * 16) = w1v;
  };
  auto writeB = [&](int buf) {  // cvt + 2x ds_write_b128
    uint4 w0v, w1v;
    w0v.x = cvtpk(bfr0.x, bfr0.y); w0v.y = cvtpk(bfr0.z, bfr0.w);
    w0v.z = cvtpk(bfr1.x, bfr1.y); w0v.w = cvtpk(bfr1.z, bfr1.w);
    w1v.x = cvtpk(bfr2.x, bfr2.y); w1v.y = cvtpk(bfr2.z, bfr2.w);
    w1v.z = cvtpk(bfr3.x, bfr3.y); w1v.w = cvtpk(bfr3.z, bfr3.w);
    *reinterpret_cast<uint4*>(ldsB + buf * 16384 + tid * 16) = w0v;
    *reinterpret_cast<uint4*>(ldsB + buf * 16384 + 8192 + tid * 16) = w1v;
  };

  // prologue -> establish entry invariant: outstanding = [A(1):4][B(1):4]
  loadA(false);
  loadB(false);
  asm volatile("s_waitcnt vmcnt(4)" ::: "memory");  // A0 landed
  writeA(0);
  loadA(false);
  asm volatile("s_waitcnt vmcnt(4)" ::: "memory");  // B0 landed
  writeB(0);
  loadB(false);
  asm volatile("s_waitcnt lgkmcnt(0)" ::: "memory");
  __builtin_amdgcn_s_barrier();

  auto group = [&](int buf, bool junk) {
    bf16x8 ar[4], br[4];
#pragma unroll
    for (int ii = 0; ii < 4; ii++)
      ar[ii] = *reinterpret_cast<const bf16x8*>(rbA + buf * 16384 + ii * 1024);
#pragma unroll
    for (int j = 0; j < 4; j++)
      br[j] = *reinterpret_cast<const bf16x8*>(rbB + buf * 16384 + j * 1024);
    asm volatile("s_waitcnt vmcnt(4)" ::: "memory");  // A(t+1) regs landed
    writeA(buf ^ 1);
    loadA(junk);
    asm volatile("s_waitcnt lgkmcnt(0)" ::: "memory");
    __builtin_amdgcn_sched_barrier(0);
    __builtin_amdgcn_s_setprio(1);
#pragma unroll
    for (int ii = 0; ii < 4; ii++)
#pragma unroll
      for (int j = 0; j < 4; j++)
        acc[ii][j] = mfma32(ar[ii], br[j], acc[ii][j]);
    __builtin_amdgcn_s_setprio(0);
    __builtin_amdgcn_s_barrier();                     // close phase 0
#pragma unroll
    for (int ii = 0; ii < 4; ii++)
      ar[ii] = *reinterpret_cast<const bf16x8*>(rbA + buf * 16384 + 4096 + ii * 1024);
    asm volatile("s_waitcnt vmcnt(4)" ::: "memory");  // B(t+1) regs landed
    writeB(buf ^ 1);
    loadB(junk);
    asm volatile("s_waitcnt lgkmcnt(0)" ::: "memory");
    __builtin_amdgcn_sched_barrier(0);
    __builtin_amdgcn_s_setprio(1);
#pragma unroll
    for (int ii = 0; ii < 4; ii++)
#pragma unroll
      for (int j = 0; j < 4; j++)
        acc[4 + ii][j] = mfma32(ar[ii], br[j], acc[4 + ii][j]);
    __builtin_amdgcn_s_setprio(0);
    __builtin_amdgcn_s_barrier();                     // close phase 1
  };

#pragma unroll 1
  for (int it = 0; it < 16; ++it) {  // 32 K-tiles of 32
    group(0, it == 15);
    group(1, it == 15);
  }
  asm volatile("s_waitcnt vmcnt(0)" ::: "memory");  // drain junk loads

  const float scale = which == 0 ? 0.125f * LOG2E : 1.0f;
#pragma unroll
  for (int i = 0; i < 8; i++) {
#pragma unroll
    for (int j = 0; j < 4; j++) {
      const int colg = n0 + wc * 64 + j * 16 + rr;
      const float bvv = bq_[colg];
      if (which == 2) {  // V^T layout [B,H,DK,S]
        const int rowbase = m0 + wr * 128 + i * 16 + g * 4;
        const int bb = rowbase >> 11, s = rowbase & 2047;
        const int hh = colg >> 6, d = colg & 63;
        uint2 val;
        val.x = (unsigned int)f2bf(acc[i][j][0] + bvv) | ((unsigned int)f2bf(acc[i][j][1] + bvv) << 16);
        val.y = (unsigned int)f2bf(acc[i][j][2] + bvv) | ((unsigned int)f2bf(acc[i][j][3] + bvv) << 16);
        *reinterpret_cast<uint2*>(Qb + 2 * NE + ((long)((bb * CH + hh) * CD + d)) * CS + s) = val;
      } else {
        unsigned short* outp = Qb + (long)which * NE;
#pragma unroll
        for (int r = 0; r < 4; r++) {
          const int row = m0 + wr * 128 + i * 16 + g * 4 + r;
          outp[(long)row * CE + colg] = f2bf((acc[i][j][r] + bvv) * scale);
        }
      }
    }
  }
}

// ---------------- WO GEMM: 128x64 tile, 512 blocks (unchanged) ----------------
__global__ __launch_bounds__(256) void gemm_wo(const unsigned short* __restrict__ A,
                                               const unsigned short* __restrict__ W,
                                               const float* __restrict__ bias,
                                               float* __restrict__ out) {
  __shared__ __align__(16) unsigned short As[128 * 64];
  __shared__ __align__(16) unsigned short Bs[64 * 64];
  const int tid = threadIdx.x;
  const int lane = tid & 63, wave = tid >> 6;
  const int wm = (wave >> 1) * 64, wn = (wave & 1) * 32;
  const int g = lane >> 4, rr = lane & 15;
  const int m0 = blockIdx.x * 128, n0 = blockIdx.y * 64;
  const int K = CE;
  f32x4 acc[4][2] = {};

  for (int k0 = 0; k0 < K; k0 += 64) {
#pragma unroll
    for (int t = 0; t < 4; t++) {
      const int u = t * 256 + tid;
      const int row = u >> 3, ce = (u & 7) * 8;
      stage16(A + (long)(m0 + row) * K + k0 + ce, (char*)As + (t * 256 + (tid & 192)) * 16);
    }
#pragma unroll
    for (int t = 0; t < 2; t++) {
      const int u = t * 256 + tid;
      const int row = u >> 3, ce = (u & 7) * 8;
      stage16(W + (long)(n0 + row) * K + k0 + ce, (char*)Bs + (t * 256 + (tid & 192)) * 16);
    }
    __syncthreads();
#pragma unroll
    for (int kk = 0; kk < 2; kk++) {
      bf16x8 af[4], bfr[2];
#pragma unroll
      for (int i = 0; i < 4; i++)
        af[i] = *reinterpret_cast<const bf16x8*>(&As[(wm + i * 16 + rr) * 64 + kk * 32 + g * 8]);
#pragma unroll
      for (int j = 0; j < 2; j++)
        bfr[j] = *reinterpret_cast<const bf16x8*>(&Bs[(wn + j * 16 + rr) * 64 + kk * 32 + g * 8]);
#pragma unroll
      for (int i = 0; i < 4; i++)
#pragma unroll
        for (int j = 0; j < 2; j++)
          acc[i][j] = mfma32(af[i], bfr[j], acc[i][j]);
    }
    __syncthreads();
  }

#pragma unroll
  for (int i = 0; i < 4; i++)
#pragma unroll
    for (int j = 0; j < 2; j++) {
      const int colg = n0 + wn + j * 16 + rr;
      const float bvv = bias[colg];
#pragma unroll
      for (int r = 0; r < 4; r++) {
        const int row = m0 + wm + i * 16 + g * 4 + r;
        out[(long)row * CE + colg] = acc[i][j][r] + bvv;
      }
    }
}

// ---------------- Flash attention v14: 8 waves, QBLK=256 (K/V staged once per 256 q) ----------------
// grid (16, 8, 2) = 256 blocks = 1/CU, 8 waves each (same residency as 2x4 before).
// Per 128-key tile: stage = 4 vmem/thread (K: t<2 rows t*64+w*8+rr8; V: half=t, row w*8+rr8);
// mb = 8 vmem. Head wait = vmcnt(12). Per-wave state identical to v13 (32 q/wave).
__global__ __launch_bounds__(512, 2) void attn_kernel(const unsigned short* __restrict__ Qb,
                                                      const unsigned short* __restrict__ Kb,
                                                      const unsigned short* __restrict__ Vtw,
                                                      const unsigned short* __restrict__ mb16,
                                                      const int* __restrict__ mask,
                                                      unsigned short* __restrict__ AO) {
  __shared__ __align__(16) unsigned char lds[65536];
  const int h = blockIdx.x, qt = blockIdx.y, b = blockIdx.z;
  const int tid = threadIdx.x;
  const int lane = tid & 63, w = tid >> 6;   // w 0..7
  const int g = lane >> 4, c = lane & 15;
  const int qbase = qt * 256 + w * 32;

  bf16x8 qf[2][2];
#pragma unroll
  for (int qb = 0; qb < 2; qb++) {
    const unsigned short* Qrow = Qb + ((long)b * CS + qbase + qb * 16 + c) * CE + h * CD;
    qf[qb][0] = *reinterpret_cast<const bf16x8*>(Qrow + g * 8);
    qf[qb][1] = *reinterpret_cast<const bf16x8*>(Qrow + 32 + g * 8);
    if (mask[b * CS + qbase + qb * 16 + c] == 0) {
      qf[qb][0] = bf16x8{}; qf[qb][1] = bf16x8{};
    }
  }

  // stage sources: per thread 2 K rows + 2 V rows (one per half)
  const unsigned char *kg[2], *vg[2];
  {
    const unsigned char* Ksrc = (const unsigned char*)(Kb + (long)b * CS * CE + h * CD);
    const unsigned char* Vsrc = (const unsigned char*)(Vtw + (long)(b * CH + h) * CD * CS);
    const int rr8 = lane >> 3;
    const int csw = ((lane & 7) << 4) ^ (rr8 << 4);
#pragma unroll
    for (int t = 0; t < 2; t++) {
      const int krow = t * 64 + w * 8 + rr8;      // 0..127
      const int key = (krow & 96) + ((krow >> 2) & 3) * 8 + ((krow >> 4) & 1) * 4 + (krow & 3);
      kg[t] = Ksrc + (long)key * (CE * 2) + csw;
      const int vrow = w * 8 + rr8;               // 0..63 (d-row)
      vg[t] = Vsrc + (long)vrow * (CS * 2) + t * 128 + csw;  // half t = keys t*64..+63
    }
  }
  const int sw = (c & 7) << 4;
  const unsigned char* rb0 = lds + c * 128 + ((g * 16) ^ sw);
  const unsigned char* rb1 = lds + c * 128 + ((64 + g * 16) ^ sw);

  const unsigned short* mbp0 = mb16 + ((long)b * CS + qbase + c) * CS + g * 8;
  const unsigned short* mbp1 = mb16 + ((long)b * CS + qbase + 16 + c) * CS + g * 8;

  f32x4 o[2][4] = {};
  f32x4 lsum4[2] = {};
  uint4 mbr[2][4];

  auto stage = [&](int bo) {  // 4 vmem/thread: K[128x128B] + V[2 half x 64x128B]
    unsigned char* kbuf = lds + bo;
    unsigned char* vbuf = lds + bo + 16384;
#pragma unroll
    for (int t = 0; t < 2; t++) {
      stage16(kg[t], kbuf + t * 8192 + w * 1024);
      stage16(vg[t], vbuf + t * 8192 + w * 1024);
      kg[t] += 128 * CE * 2;
      vg[t] += 128 * 2;
    }
  };
  auto load_mb = [&](bool adv) {  // 8 vmem
#pragma unroll
    for (int kb = 0; kb < 4; kb++) {
      mbr[0][kb] = *reinterpret_cast<const uint4*>(mbp0 + kb * 32);
      mbr[1][kb] = *reinterpret_cast<const uint4*>(mbp1 + kb * 32);
    }
    if (adv) { mbp0 += 128; mbp1 += 128; }
  };

  auto compute = [&](int bo, bool adv) {
    f32x4 sf[2][8];
    __builtin_amdgcn_s_setprio(1);
#pragma unroll
    for (int cb = 0; cb < 8; cb++) {
      const bf16x8 kf0 = *reinterpret_cast<const bf16x8*>(rb0 + bo + cb * 2048);
      const bf16x8 kf1 = *reinterpret_cast<const bf16x8*>(rb1 + bo + cb * 2048);
#pragma unroll
      for (int qb = 0; qb < 2; qb++) {
        const uint4 m = mbr[qb][cb >> 1];
        const f32x4 ci = (cb & 1) ? unpk(m.z, m.w) : unpk(m.x, m.y);
        f32x4 t = mfma32(kf0, qf[qb][0], ci);
        sf[qb][cb] = mfma32(kf1, qf[qb][1], t);
      }
    }
    __builtin_amdgcn_s_setprio(0);
    load_mb(adv);
    uint4 pw[2][4];
#pragma unroll
    for (int qb = 0; qb < 2; qb++)
#pragma unroll
      for (int kb = 0; kb < 4; kb++)
#pragma unroll
        for (int half = 0; half < 2; half++) {
          const int cb = 2 * kb + half;
          f32x4 pv;
          pv[0] = exp2r(sf[qb][cb][0]);
          pv[1] = exp2r(sf[qb][cb][1]);
          pv[2] = exp2r(sf[qb][cb][2]);
          pv[3] = exp2r(sf[qb][cb][3]);
          lsum4[qb] = lsum4[qb] + pv;
          if (half == 0) { pw[qb][kb].x = cvtpk(pv[0], pv[1]); pw[qb][kb].y = cvtpk(pv[2], pv[3]); }
          else           { pw[qb][kb].z = cvtpk(pv[0], pv[1]); pw[qb][kb].w = cvtpk(pv[2], pv[3]); }
        }
    __builtin_amdgcn_s_setprio(1);
#pragma unroll
    for (int nb = 0; nb < 4; nb++) {
#pragma unroll
      for (int kb = 0; kb < 4; kb++) {
        const unsigned char* rbx = (kb & 1) ? rb1 : rb0;
        const bf16x8 vf = *reinterpret_cast<const bf16x8*>(
            rbx + bo + 16384 + (kb >> 1) * 8192 + nb * 2048);
#pragma unroll
        for (int qb = 0; qb < 2; qb++)
          o[qb][nb] = mfma32(vf, __builtin_bit_cast(bf16x8, pw[qb][kb]), o[qb][nb]);
      }
    }
    __builtin_amdgcn_s_setprio(0);
  };

  stage(0);
  load_mb(true);
  stage(32768);

#pragma unroll 1
  for (int it = 0; it < 8; ++it) {  // 16 tiles of 128 keys
    asm volatile("s_waitcnt vmcnt(12)" ::: "memory");  // retire stage(t); keep mb+stage(t+1)
    __builtin_amdgcn_s_barrier();
    __builtin_amdgcn_sched_barrier(0);
    compute(0, it < 7);
    __builtin_amdgcn_sched_barrier(0);
    __builtin_amdgcn_s_barrier();
    stage(0);
    asm volatile("s_waitcnt vmcnt(12)" ::: "memory");
    __builtin_amdgcn_s_barrier();
    __builtin_amdgcn_sched_barrier(0);
    compute(32768, it < 7);
    __builtin_amdgcn_sched_barrier(0);
    __builtin_amdgcn_s_barrier();
    stage(32768);
  }

#pragma unroll
  for (int qb = 0; qb < 2; qb++) {
    float lsum = (lsum4[qb][0] + lsum4[qb][1]) + (lsum4[qb][2] + lsum4[qb][3]);
    lsum += __shfl_xor(lsum, 16, 64);
    lsum += __shfl_xor(lsum, 32, 64);
    const float linv = 1.0f / lsum;
    unsigned short* Orow = AO + ((long)b * CS + qbase + qb * 16 + c) * CE + h * CD;
#pragma unroll
    for (int nb = 0; nb < 4; nb++) {
      uint2 val;
      val.x = (unsigned int)f2bf(o[qb][nb][0] * linv) | ((unsigned int)f2bf(o[qb][nb][1] * linv) << 16);
      val.y = (unsigned int)f2bf(o[qb][nb][2] * linv) | ((unsigned int)f2bf(o[qb][nb][3] * linv) << 16);
      *reinterpret_cast<uint2*>(Orow + nb * 16 + g * 4) = val;
    }
  }
  asm volatile("s_waitcnt vmcnt(0)" ::: "memory");  // drain junk stages before endpgm
}

// ---------------- host ----------------
extern "C" void kernel_launch(void* const* d_in, const int* in_sizes, int n_in,
                              void* d_out, int out_size, void* d_ws, size_t ws_size,
                              hipStream_t stream) {
  (void)in_sizes; (void)n_in; (void)out_size; (void)ws_size;
  const float* x    = (const float*)d_in[0];
  const float* kv   = (const float*)d_in[1];
  const int*   mask = (const int*)d_in[2];
  const float* ab   = (const float*)d_in[3];
  const float* WQw  = (const float*)d_in[4];
  const float* WQb  = (const float*)d_in[5];
  const float* WKw  = (const float*)d_in[6];
  const float* WKb  = (const float*)d_in[7];
  const float* WVw  = (const float*)d_in[8];
  const float* WVb  = (const float*)d_in[9];
  const float* WOw  = (const float*)d_in[10];
  const float* WOb  = (const float*)d_in[11];
  float* out = (float*)d_out;

  const long NE = (long)CB * CS * CE;  // 4,194,304
  const long WE = (long)CE * CE;       // 1,048,576
  unsigned short* ws  = (unsigned short*)d_ws;
  unsigned short* wob = ws + 3 * WE;   // WO bf16 (written by qkv side-blocks)
  unsigned short* Qb  = wob + WE;      // Q | K | Vt | AO contiguous
  unsigned short* AO  = Qb + 3 * NE;
  unsigned short* mb16 = AO + NE;      // CB*CS*CS bf16; total ws use = 58.7 MB

  // single fused front kernel: QKV GEMM (f32 inputs) + mbias + WO-cvt side work
  gemm_qkv<<<dim3(192 + 256 + 32), 512, 0, stream>>>(
      x, kv, WQw, WKw, WVw, WQb, WKb, WVb, Qb, ab, mask, mb16, WOw, wob);

  attn_kernel<<<dim3(CH, CS / 256, CB), 512, 0, stream>>>(
      Qb, Qb + NE, Qb + 2 * NE, mb16, mask, AO);

  gemm_wo<<<dim3(32, 16), 256, 0, stream>>>(AO, wob, WOb, out);
}